// Round 10
// baseline (241.551 us; speedup 1.0000x reference)
//
#include <hip/hip_runtime.h>
#include <math.h>

#define D_MODEL 768
#define NHEADS  12
#define HDIM    64
#define SEQ     1024
#define BATCH   8
#define NBH     (BATCH*NHEADS)          // 96
#define M_TOTAL (BATCH*SEQ)             // 8192
#define KT_D    (D_MODEL/32)            // 24
#define QKV_COLS (3*D_MODEL)            // 2304

typedef __attribute__((ext_vector_type(8))) short bf16x8;
typedef __attribute__((ext_vector_type(4))) float f32x4;

#define MFMA16(a,b,c) __builtin_amdgcn_mfma_f32_16x16x32_bf16((a),(b),(c),0,0,0)

// Q pre-scale: 1/sqrt(64) * log2(e) so softmax runs in exp2 domain
#define QSCALE 0.18033688011112042f

// ---- helpers ----------------------------------------------------------------
__device__ inline unsigned short f2bf(float f) {
    unsigned u = __float_as_uint(f);
    u += 0x7FFFu + ((u >> 16) & 1u);
    return (unsigned short)(u >> 16);
}
__device__ inline float bf2f(unsigned short h) {
    return __uint_as_float(((unsigned)h) << 16);
}
__device__ inline void split2(float x, unsigned short& hi, unsigned short& lo) {
    hi = f2bf(x);
    lo = f2bf(x - bf2f(hi));
}
__device__ inline void gload16(const void* g, const void* l) {
    __builtin_amdgcn_global_load_lds(
        (const __attribute__((address_space(1))) unsigned*)g,
        (__attribute__((address_space(3))) unsigned*)l, 16, 0, 0);
}
__device__ inline float exp2_fast(float x) {
#if __has_builtin(__builtin_amdgcn_exp2f)
    return __builtin_amdgcn_exp2f(x);
#else
    float r; asm("v_exp_f32 %0, %1" : "=v"(r) : "v"(x)); return r;
#endif
}

// Fragment containers:
//  full subtile (hi+lo): 1024 ushorts (A-frag: lane=(row%16)+((k%32)/8)*16, slot=k%8)
//  hi-only subtile:       512 ushorts

// ---- convert x (fp32 [M][K]) -> A-fragments, HI-ONLY (gemm0 is split-2) ------
__global__ __launch_bounds__(256)
void convert_a(const float* __restrict__ src, unsigned short* __restrict__ dst,
               int total)
{
    const int gid = blockIdx.x * 256 + threadIdx.x;
    if (gid >= total) return;
    const int lane = gid & 63;
    const int sub  = gid >> 6;
    const int kt = sub % KT_D;
    const int mt = sub / KT_D;
    const float* s = src + (size_t)(mt*16 + (lane & 15)) * D_MODEL + kt*32 + (lane >> 4)*8;
    float4 v0 = *(const float4*)(s);
    float4 v1 = *(const float4*)(s + 4);
    float vv[8] = {v0.x, v0.y, v0.z, v0.w, v1.x, v1.y, v1.z, v1.w};
    union { unsigned short u[8]; bf16x8 v; } H;
    #pragma unroll
    for (int i = 0; i < 8; ++i) H.u[i] = f2bf(vv[i]);
    *(bf16x8*)(dst + (size_t)sub * 512 + lane * 8) = H.v;
}

// ---- convert weights (fp32 [K][N]) -> B-fragments, full hi+lo ----------------
__global__ __launch_bounds__(256)
void convert_b(const float* __restrict__ src, unsigned short* __restrict__ dst,
               int ldN, int total)
{
    const int gid = blockIdx.x * 256 + threadIdx.x;
    if (gid >= total) return;
    const int lane = gid & 63;
    const int sub  = gid >> 6;
    const int kt = sub % KT_D;
    const int nt = sub / KT_D;
    const int n  = nt*16 + (lane & 15);
    const int k0 = kt*32 + (lane >> 4)*8;
    const float* s = src + (size_t)k0 * ldN + n;
    union { unsigned short u[8]; bf16x8 v; } H, L;
    #pragma unroll
    for (int i = 0; i < 8; ++i) split2(s[(size_t)i * ldN], H.u[i], L.u[i]);
    unsigned short* d = dst + (size_t)sub * 1024 + lane * 8;
    *(bf16x8*)(d)       = H.v;
    *(bf16x8*)(d + 512) = L.v;
}

// ---- fragment GEMM: 128x64 tile, BK=32, 4 waves (2m x 2n), wave tile 64x32 ---
// Occupancy-first: MODE0 caps VGPR at 64 (__launch_bounds__(256,8)) -> 8
// waves/SIMD, ~8 blocks/CU; inter-block TLP hides the staging drain (m114).
// Simple stage->sync->compute structure (empirical winner at this size).
// 1-D grid, XCD swizzle: mb=(bid&7)*8+((bid>>3)&7), nb=bid>>6.
// MODE 0: A hi-only split-2; epilogue scatters Q(full)/K(hi)/V(hi) fragments.
// MODE 1: A full split-3; fp32 out + bias (grid-limited to 3 blocks/CU).
template<int MODE>
__global__ __launch_bounds__(256, MODE == 0 ? 8 : 4)
void gemm_frag(const unsigned short* __restrict__ Af,
               const unsigned short* __restrict__ Bf,
               const float* __restrict__ bias,
               float* __restrict__ outF,
               unsigned short* __restrict__ outQ,
               unsigned short* __restrict__ outK,
               unsigned short* __restrict__ outV)
{
    constexpr int ACH = (MODE == 0) ? 8 : 16;      // A 1KB-chunks per kt
    constexpr int NCH = ACH + 8;                   // + B chunks (4 subtiles full)
    __shared__ unsigned short Asm[ACH * 512];
    __shared__ unsigned short Bsm[8 * 512];
    const int t = threadIdx.x, lane = t & 63, wid = t >> 6;
    const int wr = wid >> 1, wc = wid & 1;
    const int bid = blockIdx.x;
    const int mb = (bid & 7) * 8 + ((bid >> 3) & 7);
    const int nb = bid >> 6;

    f32x4 acc[4][2] = {};

    for (int kt = 0; kt < KT_D; ++kt) {
        __syncthreads();                       // prior LDS reads done
        // stage: NCH 1KB chunks, NCH/4 per wave
        #pragma unroll
        for (int i = 0; i < NCH/4; ++i) {
            const int c = wid * (NCH/4) + i;
            const unsigned short* g;
            if (c < ACH) {
                if (MODE == 0)   // A hi-only: subtile c
                    g = Af + ((size_t)(mb*8 + c)*KT_D + kt)*512 + lane*8;
                else             // A full: subtile c>>1, plane c&1
                    g = Af + ((size_t)(mb*8 + (c >> 1))*KT_D + kt)*1024 + (c & 1)*512 + lane*8;
                gload16(g, (const char*)Asm + (size_t)c*1024);
            } else {
                const int j = c - ACH;         // B: subtile j>>1, plane j&1
                g = Bf + ((size_t)(nb*4 + (j >> 1))*KT_D + kt)*1024 + (j & 1)*512 + lane*8;
                gload16(g, (const char*)Bsm + (size_t)j*1024);
            }
        }
        __syncthreads();                       // staging complete (vmcnt drained)

        bf16x8 bh[2], bl[2];
        #pragma unroll
        for (int n = 0; n < 2; ++n) {
            bh[n] = *(const bf16x8*)(Bsm + (wc*2 + n)*1024 + lane*8);
            bl[n] = *(const bf16x8*)(Bsm + (wc*2 + n)*1024 + 512 + lane*8);
        }
        if (MODE == 0) {
            bf16x8 ah[4];
            #pragma unroll
            for (int m = 0; m < 4; ++m)
                ah[m] = *(const bf16x8*)(Asm + (wr*4 + m)*512 + lane*8);
            #pragma unroll
            for (int m = 0; m < 4; ++m)
                #pragma unroll
                for (int n = 0; n < 2; ++n) {
                    acc[m][n] = MFMA16(ah[m], bh[n], acc[m][n]);
                    acc[m][n] = MFMA16(ah[m], bl[n], acc[m][n]);
                }
        } else {
            bf16x8 ah[4], al[4];
            #pragma unroll
            for (int m = 0; m < 4; ++m) {
                ah[m] = *(const bf16x8*)(Asm + (wr*4 + m)*1024 + lane*8);
                al[m] = *(const bf16x8*)(Asm + (wr*4 + m)*1024 + 512 + lane*8);
            }
            #pragma unroll
            for (int m = 0; m < 4; ++m)
                #pragma unroll
                for (int n = 0; n < 2; ++n) {
                    acc[m][n] = MFMA16(ah[m], bh[n], acc[m][n]);
                    acc[m][n] = MFMA16(ah[m], bl[n], acc[m][n]);
                    acc[m][n] = MFMA16(al[m], bh[n], acc[m][n]);
                }
        }
    }

    const int rowW = mb*128 + wr*64;
    const int colW = nb*64 + wc*32;
    if (MODE == 1) {
        #pragma unroll
        for (int m = 0; m < 4; ++m)
            #pragma unroll
            for (int n = 0; n < 2; ++n) {
                const int col = colW + n*16 + (lane & 15);
                const float bv = bias[col];
                #pragma unroll
                for (int r = 0; r < 4; ++r) {
                    const int row = rowW + m*16 + (lane >> 4)*4 + r;
                    outF[(size_t)row * D_MODEL + col] = acc[m][n][r] + bv;
                }
            }
    } else {
        // whole block maps to ONE (which, head): nb*64 .. nb*64+63
        const int which = (nb * 64) / D_MODEL;
        const int h     = ((nb * 64) % D_MODEL) >> 6;
        #pragma unroll
        for (int m = 0; m < 4; ++m)
            #pragma unroll
            for (int n = 0; n < 2; ++n) {
                const int col = colW + n*16 + (lane & 15);
                const int d = col & 63;
                const float bv = bias[col];
                #pragma unroll
                for (int r = 0; r < 4; ++r) {
                    const int row = rowW + m*16 + (lane >> 4)*4 + r;
                    const int b = row >> 10, sq = row & 1023;
                    float val = acc[m][n][r] + bv;
                    if (which == 0) {                    // Q: full hi+lo, pre-scaled
                        val *= QSCALE;
                        const int sub = (sq >> 4)*2 + (d >> 5);
                        const int lp  = (sq & 15) + (((d & 31) >> 3) << 4);
                        unsigned short hi, lo; split2(val, hi, lo);
                        unsigned short* p = outQ + (size_t)(b*NHEADS + h)*131072
                                          + (size_t)sub*1024 + lp*8 + (d & 7);
                        p[0]   = hi;
                        p[512] = lo;
                    } else if (which == 1) {             // K: hi only
                        const int sub = (sq >> 4)*2 + (d >> 5);
                        const int lp  = (sq & 15) + (((d & 31) >> 3) << 4);
                        outK[(size_t)(b*NHEADS + h)*65536
                             + (size_t)sub*512 + lp*8 + (d & 7)] = f2bf(val);
                    } else {                             // V: hi only (B-frag)
                        const int sub = (d >> 4)*32 + (sq >> 5);
                        const int lp  = (d & 15) + (((sq & 31) >> 3) << 4);
                        outV[(size_t)(b*NHEADS + h)*65536
                             + (size_t)sub*512 + lp*8 + (sq & 7)] = f2bf(val);
                    }
                }
            }
    }
}

// ---- flash attention: 8 waves x 16 q-rows (1 m-subtile/wave), KV tiles of 64 -
// Same 128 q-rows/block and K/V staging as before, but 8 waves -> 24 waves/CU
// (2x TLP, zero extra global traffic). dbuf staging; K,V hi-only; QK split-2;
// PV hi-only; MFMA-ones rowsum; defer-max THR=8; exp2 domain. LDS 48KB.
__global__ __launch_bounds__(512, 6)
void attn_frag(const unsigned short* __restrict__ Qf,
               const unsigned short* __restrict__ Kf,
               const unsigned short* __restrict__ Vf,
               unsigned short* __restrict__ Cf)
{
    __shared__ unsigned short Ksm[2][8 * 512];   // dbuf: 4 jn x 2 kt hi subtiles
    __shared__ unsigned short Vsm[2][8 * 512];   // dbuf: 4 dt x 2 kt2 hi subtiles
    __shared__ unsigned short Psm[8 * 1024];     // per-wave P: 2 subtiles x 512 bf16

    const int t = threadIdx.x, lane = t & 63, wid = t >> 6;   // wid 0..7
    // XCD swizzle: all 8 q-blocks of one (b,h) land on the same XCD
    const int bid = blockIdx.x;
    const int qb  = (bid >> 3) & 7;
    const int bh  = (bid & 7) * 12 + (bid >> 6);
    const int mt0 = qb*8 + wid;                // wave's q-subtile (of 64)
    const size_t qBase = (size_t)bh * 131072;
    const size_t kBase = (size_t)bh * 65536;

    const int slot  = lane & 7;
    const int colg  = (lane & 15) >> 3;        // 0/1
    const int qrow0 = (lane >> 4) * 4;         // 0,4,8,12

    // stage K/V hi subtiles of kv-tile jt into buffer b (2 chunks per wave)
    auto stage = [&](int b, int jt) {
        #pragma unroll
        for (int i = 0; i < 2; ++i) {
            const int ch = wid*2 + i;
            if (ch < 8) {
                const unsigned short* gk = Kf + kBase + (size_t)(jt*8 + ch)*512;
                gload16(gk + lane*8, (const char*)&Ksm[b][0] + (size_t)ch*1024);
            } else {
                const int cv = ch - 8;                 // dt = cv>>1, kt2 = cv&1
                const unsigned short* gv = Vf + kBase
                    + (size_t)((cv >> 1)*32 + jt*2 + (cv & 1))*512;
                gload16(gv + lane*8, (const char*)&Vsm[b][0] + (size_t)cv*1024);
            }
        }
    };

    stage(0, 0);                               // prologue: tile 0 into buf 0

    // Q fragments in registers (already scaled by QSCALE); overlap prologue.
    bf16x8 qh[2], ql[2];
    #pragma unroll
    for (int kt = 0; kt < 2; ++kt) {
        const unsigned short* p = Qf + qBase + ((size_t)mt0*2 + kt)*1024 + lane*8;
        qh[kt] = *(const bf16x8*)(p);
        ql[kt] = *(const bf16x8*)(p + 512);
    }

    // ones B-frag for the MFMA rowsum
    bf16x8 ones;
    #pragma unroll
    for (int i = 0; i < 8; ++i) ones[i] = (short)0x3F80;

    f32x4 out[4] = {};
    f32x4 lacc = {};
    float m_run[4];
    #pragma unroll
    for (int r = 0; r < 4; ++r) m_run[r] = -INFINITY;

    unsigned short* Pw = Psm + wid * 1024;

    __syncthreads();                           // prologue stage complete

    for (int jt = 0; jt < 16; ++jt) {
        const int cur = jt & 1;
        if (jt + 1 < 16) stage(cur ^ 1, jt + 1);   // prefetch next tile (hidden)

        // S = Q K^T, split-2 (K hi only)
        f32x4 s[4] = {};
        #pragma unroll
        for (int jn = 0; jn < 4; ++jn)
            #pragma unroll
            for (int kt = 0; kt < 2; ++kt) {
                const bf16x8 kh = *(const bf16x8*)(&Ksm[cur][0] + (jn*2 + kt)*512 + lane*8);
                s[jn] = MFMA16(qh[kt], kh, s[jn]);
                s[jn] = MFMA16(ql[kt], kh, s[jn]);
            }

        // defer-max: in-lane partial max -> wave-uniform skip predicate
        float mx[4];
        int ok = 1;
        #pragma unroll
        for (int r = 0; r < 4; ++r) {
            const float v = fmaxf(fmaxf(s[0][r], s[1][r]), fmaxf(s[2][r], s[3][r]));
            mx[r] = v;
            ok &= (v <= m_run[r] + 8.0f);
        }
        if (!__all(ok)) {
            float alf[4];
            #pragma unroll
            for (int r = 0; r < 4; ++r) {
                float v = mx[r];
                #pragma unroll
                for (int msk = 1; msk < 16; msk <<= 1)
                    v = fmaxf(v, __shfl_xor(v, msk));
                const float mn = fmaxf(m_run[r], v);
                alf[r] = exp2_fast(m_run[r] - mn);
                m_run[r] = mn;
            }
            #pragma unroll
            for (int dt = 0; dt < 4; ++dt)
                #pragma unroll
                for (int r = 0; r < 4; ++r)
                    out[dt][r] *= alf[r];
            #pragma unroll
            for (int r = 0; r < 4; ++r)
                lacc[r] *= alf[r];
        }

        // P = exp2(s - m) -> bf16-hi into swizzled A-frag LDS (wave-local)
        #pragma unroll
        for (int r = 0; r < 4; ++r) {
            const float mb_ = m_run[r];
            const int tl   = qrow0 + r + (colg << 4);
            const int idxb = ((tl << 3) | slot) ^ (tl & 0x18);
            #pragma unroll
            for (int jn = 0; jn < 4; ++jn)
                Pw[(jn >> 1)*512 + idxb + ((jn & 1) << 8)]
                    = f2bf(exp2_fast(s[jn][r] - mb_));
        }

        // PV + MFMA rowsum: read P back as bf16x8 A-frags (wave-local)
        const int rdswz = (lane*8) ^ (lane & 0x18);
        #pragma unroll
        for (int kt2 = 0; kt2 < 2; ++kt2) {
            const bf16x8 pa = *(const bf16x8*)(Pw + kt2*512 + rdswz);
            #pragma unroll
            for (int dt = 0; dt < 4; ++dt) {
                const bf16x8 vh = *(const bf16x8*)(&Vsm[cur][0] + (dt*2 + kt2)*512 + lane*8);
                out[dt] = MFMA16(pa, vh, out[dt]);
            }
            lacc = MFMA16(pa, ones, lacc);
        }

        __syncthreads();   // next tile staged by ALL waves; this tile's reads done
    }

    // epilogue: ctx / l  ->  proj-GEMM A-fragments (full hi+lo)
    const int b = bh / NHEADS, h = bh % NHEADS;
    #pragma unroll
    for (int r = 0; r < 4; ++r) {
        const float inv = 1.0f / lacc[r];
        const int sq = mt0*16 + qrow0 + r;
        const int mrow = b*SEQ + sq;
        #pragma unroll
        for (int dt = 0; dt < 4; ++dt) {
            const int c = h*64 + dt*16 + (lane & 15);
            const float val = out[dt][r] * inv;
            unsigned short hi, lo; split2(val, hi, lo);
            unsigned short* p = Cf + ((size_t)(mrow >> 4)*KT_D + (c >> 5))*1024
                              + ((mrow & 15) + (((c & 31) >> 3) << 4))*8 + (c & 7);
            p[0]   = hi;
            p[512] = lo;
        }
    }
}

// ---------------------------------------------------------------------------
extern "C" void kernel_launch(void* const* d_in, const int* in_sizes, int n_in,
                              void* d_out, int out_size, void* d_ws, size_t ws_size,
                              hipStream_t stream)
{
    const float* x      = (const float*)d_in[0];
    const float* w_qkv  = (const float*)d_in[1];
    const float* b_qkv  = (const float*)d_in[2];
    const float* w_proj = (const float*)d_in[3];
    const float* b_proj = (const float*)d_in[4];
    float* out = (float*)d_out;

    unsigned short* ws = (unsigned short*)d_ws;
    unsigned short* Xf = ws;                    // 12288 sub * 512    =  6,291,456
    unsigned short* Wq = Xf + 6291456;          // 3456 sub * 1024    =  3,538,944
    unsigned short* Wp = Wq + 3538944;          // 1152 sub * 1024    =  1,179,648
    unsigned short* Qf = Wp + 1179648;          // 96 * 131072        = 12,582,912
    unsigned short* Kf = Qf + 12582912;         // 96 * 65536         =  6,291,456
    unsigned short* Vf = Kf + 6291456;          // 96 * 65536         =  6,291,456
    unsigned short* Cf = Vf + 6291456;          // 12288 sub * 1024   = 12,582,912
    // total ~49.7M ushorts = ~95 MB of d_ws

    convert_a<<<dim3(3072), 256, 0, stream>>>(x, Xf, 786432);
    convert_b<<<dim3(864),  256, 0, stream>>>(w_qkv, Wq, QKV_COLS, 221184);
    convert_b<<<dim3(288),  256, 0, stream>>>(w_proj, Wp, D_MODEL, 73728);

    gemm_frag<0><<<dim3(2304), 256, 0, stream>>>(Xf, Wq, b_qkv, nullptr, Qf, Kf, Vf);
    attn_frag<<<dim3(768), 512, 0, stream>>>(Qf, Kf, Vf, Cf);
    gemm_frag<1><<<dim3(768), 256, 0, stream>>>(Cf, Wp, b_proj, out,
                                                nullptr, nullptr, nullptr);
}

// Round 11
// 179.001 us; speedup vs baseline: 1.3494x; 1.3494x over previous
//
#include <hip/hip_runtime.h>
#include <math.h>

#define D_MODEL 768
#define NHEADS  12
#define HDIM    64
#define SEQ     1024
#define BATCH   8
#define NBH     (BATCH*NHEADS)          // 96
#define M_TOTAL (BATCH*SEQ)             // 8192
#define KT_D    (D_MODEL/32)            // 24
#define QKV_COLS (3*D_MODEL)            // 2304

typedef __attribute__((ext_vector_type(8))) short bf16x8;
typedef __attribute__((ext_vector_type(4))) float f32x4;

#define MFMA16(a,b,c) __builtin_amdgcn_mfma_f32_16x16x32_bf16((a),(b),(c),0,0,0)

// Q pre-scale: 1/sqrt(64) * log2(e) so softmax runs in exp2 domain
#define QSCALE 0.18033688011112042f

// ---- helpers ----------------------------------------------------------------
__device__ inline unsigned short f2bf(float f) {
    unsigned u = __float_as_uint(f);
    u += 0x7FFFu + ((u >> 16) & 1u);
    return (unsigned short)(u >> 16);
}
__device__ inline float bf2f(unsigned short h) {
    return __uint_as_float(((unsigned)h) << 16);
}
__device__ inline void split2(float x, unsigned short& hi, unsigned short& lo) {
    hi = f2bf(x);
    lo = f2bf(x - bf2f(hi));
}
__device__ inline void gload16(const void* g, const void* l) {
    __builtin_amdgcn_global_load_lds(
        (const __attribute__((address_space(1))) unsigned*)g,
        (__attribute__((address_space(3))) unsigned*)l, 16, 0, 0);
}
__device__ inline float exp2_fast(float x) {
#if __has_builtin(__builtin_amdgcn_exp2f)
    return __builtin_amdgcn_exp2f(x);
#else
    float r; asm("v_exp_f32 %0, %1" : "=v"(r) : "v"(x)); return r;
#endif
}

// Fragment containers:
//  full subtile (hi+lo): 1024 ushorts (A-frag: lane=(row%16)+((k%32)/8)*16, slot=k%8)
//  hi-only subtile:       512 ushorts

// ---- convert x (fp32 [M][K]) -> A-fragments, HI-ONLY (gemm0 is split-2) ------
__global__ __launch_bounds__(256)
void convert_a(const float* __restrict__ src, unsigned short* __restrict__ dst,
               int total)
{
    const int gid = blockIdx.x * 256 + threadIdx.x;
    if (gid >= total) return;
    const int lane = gid & 63;
    const int sub  = gid >> 6;
    const int kt = sub % KT_D;
    const int mt = sub / KT_D;
    const float* s = src + (size_t)(mt*16 + (lane & 15)) * D_MODEL + kt*32 + (lane >> 4)*8;
    float4 v0 = *(const float4*)(s);
    float4 v1 = *(const float4*)(s + 4);
    float vv[8] = {v0.x, v0.y, v0.z, v0.w, v1.x, v1.y, v1.z, v1.w};
    union { unsigned short u[8]; bf16x8 v; } H;
    #pragma unroll
    for (int i = 0; i < 8; ++i) H.u[i] = f2bf(vv[i]);
    *(bf16x8*)(dst + (size_t)sub * 512 + lane * 8) = H.v;
}

// ---- convert weights (fp32 [K][N]) -> B-fragments, full hi+lo ----------------
__global__ __launch_bounds__(256)
void convert_b(const float* __restrict__ src, unsigned short* __restrict__ dst,
               int ldN, int total)
{
    const int gid = blockIdx.x * 256 + threadIdx.x;
    if (gid >= total) return;
    const int lane = gid & 63;
    const int sub  = gid >> 6;
    const int kt = sub % KT_D;
    const int nt = sub / KT_D;
    const int n  = nt*16 + (lane & 15);
    const int k0 = kt*32 + (lane >> 4)*8;
    const float* s = src + (size_t)k0 * ldN + n;
    union { unsigned short u[8]; bf16x8 v; } H, L;
    #pragma unroll
    for (int i = 0; i < 8; ++i) split2(s[(size_t)i * ldN], H.u[i], L.u[i]);
    unsigned short* d = dst + (size_t)sub * 1024 + lane * 8;
    *(bf16x8*)(d)       = H.v;
    *(bf16x8*)(d + 512) = L.v;
}

// ---- fragment GEMM: 128x64 tile, BK=32, 4 waves (2m x 2n), wave tile 64x32 ---
// Occupancy via small acc (8 f32x4) at __launch_bounds__(256,4): 44 VGPR, no
// spill (the (256,8) experiment spilled acc to scratch: VGPR 32, FETCH 2x,
// MfmaUtil halved — round 10). Inter-block TLP hides the staging drain (m114).
// 1-D grid, XCD swizzle: mb=(bid&7)*8+((bid>>3)&7), nb=bid>>6.
// MODE 0: A hi-only split-2; epilogue scatters Q(full)/K(hi)/V(hi) fragments.
// MODE 1: A full split-3; fp32 out + bias.
template<int MODE>
__global__ __launch_bounds__(256, 4)
void gemm_frag(const unsigned short* __restrict__ Af,
               const unsigned short* __restrict__ Bf,
               const float* __restrict__ bias,
               float* __restrict__ outF,
               unsigned short* __restrict__ outQ,
               unsigned short* __restrict__ outK,
               unsigned short* __restrict__ outV)
{
    constexpr int ACH = (MODE == 0) ? 8 : 16;      // A 1KB-chunks per kt
    constexpr int NCH = ACH + 8;                   // + B chunks (4 subtiles full)
    __shared__ unsigned short Asm[ACH * 512];
    __shared__ unsigned short Bsm[8 * 512];
    const int t = threadIdx.x, lane = t & 63, wid = t >> 6;
    const int wr = wid >> 1, wc = wid & 1;
    const int bid = blockIdx.x;
    const int mb = (bid & 7) * 8 + ((bid >> 3) & 7);
    const int nb = bid >> 6;

    f32x4 acc[4][2] = {};

    for (int kt = 0; kt < KT_D; ++kt) {
        __syncthreads();                       // prior LDS reads done
        // stage: NCH 1KB chunks, NCH/4 per wave
        #pragma unroll
        for (int i = 0; i < NCH/4; ++i) {
            const int c = wid * (NCH/4) + i;
            const unsigned short* g;
            if (c < ACH) {
                if (MODE == 0)   // A hi-only: subtile c
                    g = Af + ((size_t)(mb*8 + c)*KT_D + kt)*512 + lane*8;
                else             // A full: subtile c>>1, plane c&1
                    g = Af + ((size_t)(mb*8 + (c >> 1))*KT_D + kt)*1024 + (c & 1)*512 + lane*8;
                gload16(g, (const char*)Asm + (size_t)c*1024);
            } else {
                const int j = c - ACH;         // B: subtile j>>1, plane j&1
                g = Bf + ((size_t)(nb*4 + (j >> 1))*KT_D + kt)*1024 + (j & 1)*512 + lane*8;
                gload16(g, (const char*)Bsm + (size_t)j*1024);
            }
        }
        __syncthreads();                       // staging complete (vmcnt drained)

        bf16x8 bh[2], bl[2];
        #pragma unroll
        for (int n = 0; n < 2; ++n) {
            bh[n] = *(const bf16x8*)(Bsm + (wc*2 + n)*1024 + lane*8);
            bl[n] = *(const bf16x8*)(Bsm + (wc*2 + n)*1024 + 512 + lane*8);
        }
        if (MODE == 0) {
            bf16x8 ah[4];
            #pragma unroll
            for (int m = 0; m < 4; ++m)
                ah[m] = *(const bf16x8*)(Asm + (wr*4 + m)*512 + lane*8);
            #pragma unroll
            for (int m = 0; m < 4; ++m)
                #pragma unroll
                for (int n = 0; n < 2; ++n) {
                    acc[m][n] = MFMA16(ah[m], bh[n], acc[m][n]);
                    acc[m][n] = MFMA16(ah[m], bl[n], acc[m][n]);
                }
        } else {
            bf16x8 ah[4], al[4];
            #pragma unroll
            for (int m = 0; m < 4; ++m) {
                ah[m] = *(const bf16x8*)(Asm + (wr*4 + m)*1024 + lane*8);
                al[m] = *(const bf16x8*)(Asm + (wr*4 + m)*1024 + 512 + lane*8);
            }
            #pragma unroll
            for (int m = 0; m < 4; ++m)
                #pragma unroll
                for (int n = 0; n < 2; ++n) {
                    acc[m][n] = MFMA16(ah[m], bh[n], acc[m][n]);
                    acc[m][n] = MFMA16(ah[m], bl[n], acc[m][n]);
                    acc[m][n] = MFMA16(al[m], bh[n], acc[m][n]);
                }
        }
    }

    const int rowW = mb*128 + wr*64;
    const int colW = nb*64 + wc*32;
    if (MODE == 1) {
        #pragma unroll
        for (int m = 0; m < 4; ++m)
            #pragma unroll
            for (int n = 0; n < 2; ++n) {
                const int col = colW + n*16 + (lane & 15);
                const float bv = bias[col];
                #pragma unroll
                for (int r = 0; r < 4; ++r) {
                    const int row = rowW + m*16 + (lane >> 4)*4 + r;
                    outF[(size_t)row * D_MODEL + col] = acc[m][n][r] + bv;
                }
            }
    } else {
        // whole block maps to ONE (which, head): nb*64 .. nb*64+63
        const int which = (nb * 64) / D_MODEL;
        const int h     = ((nb * 64) % D_MODEL) >> 6;
        #pragma unroll
        for (int m = 0; m < 4; ++m)
            #pragma unroll
            for (int n = 0; n < 2; ++n) {
                const int col = colW + n*16 + (lane & 15);
                const int d = col & 63;
                const float bv = bias[col];
                #pragma unroll
                for (int r = 0; r < 4; ++r) {
                    const int row = rowW + m*16 + (lane >> 4)*4 + r;
                    const int b = row >> 10, sq = row & 1023;
                    float val = acc[m][n][r] + bv;
                    if (which == 0) {                    // Q: full hi+lo, pre-scaled
                        val *= QSCALE;
                        const int sub = (sq >> 4)*2 + (d >> 5);
                        const int lp  = (sq & 15) + (((d & 31) >> 3) << 4);
                        unsigned short hi, lo; split2(val, hi, lo);
                        unsigned short* p = outQ + (size_t)(b*NHEADS + h)*131072
                                          + (size_t)sub*1024 + lp*8 + (d & 7);
                        p[0]   = hi;
                        p[512] = lo;
                    } else if (which == 1) {             // K: hi only
                        const int sub = (sq >> 4)*2 + (d >> 5);
                        const int lp  = (sq & 15) + (((d & 31) >> 3) << 4);
                        outK[(size_t)(b*NHEADS + h)*65536
                             + (size_t)sub*512 + lp*8 + (d & 7)] = f2bf(val);
                    } else {                             // V: hi only (B-frag)
                        const int sub = (d >> 4)*32 + (sq >> 5);
                        const int lp  = (d & 15) + (((sq & 31) >> 3) << 4);
                        outV[(size_t)(b*NHEADS + h)*65536
                             + (size_t)sub*512 + lp*8 + (sq & 7)] = f2bf(val);
                    }
                }
            }
    }
}

// ---- flash attention: 8 waves x 16 q-rows (1 m-subtile/wave), KV tiles of 64 -
// Same 128 q-rows/block and K/V staging as the 4-wave version, but 8 waves ->
// 24 waves/CU (2x TLP, zero extra global traffic). dbuf staging; K,V hi-only;
// QK split-2; PV hi-only; MFMA-ones rowsum; defer-max THR=8; exp2 domain.
__global__ __launch_bounds__(512, 6)
void attn_frag(const unsigned short* __restrict__ Qf,
               const unsigned short* __restrict__ Kf,
               const unsigned short* __restrict__ Vf,
               unsigned short* __restrict__ Cf)
{
    __shared__ unsigned short Ksm[2][8 * 512];   // dbuf: 4 jn x 2 kt hi subtiles
    __shared__ unsigned short Vsm[2][8 * 512];   // dbuf: 4 dt x 2 kt2 hi subtiles
    __shared__ unsigned short Psm[8 * 1024];     // per-wave P: 2 subtiles x 512 bf16

    const int t = threadIdx.x, lane = t & 63, wid = t >> 6;   // wid 0..7
    // XCD swizzle: all 8 q-blocks of one (b,h) land on the same XCD
    const int bid = blockIdx.x;
    const int qb  = (bid >> 3) & 7;
    const int bh  = (bid & 7) * 12 + (bid >> 6);
    const int mt0 = qb*8 + wid;                // wave's q-subtile (of 64)
    const size_t qBase = (size_t)bh * 131072;
    const size_t kBase = (size_t)bh * 65536;

    const int slot  = lane & 7;
    const int colg  = (lane & 15) >> 3;        // 0/1
    const int qrow0 = (lane >> 4) * 4;         // 0,4,8,12

    // stage K/V hi subtiles of kv-tile jt into buffer b (2 chunks per wave)
    auto stage = [&](int b, int jt) {
        #pragma unroll
        for (int i = 0; i < 2; ++i) {
            const int ch = wid*2 + i;
            if (ch < 8) {
                const unsigned short* gk = Kf + kBase + (size_t)(jt*8 + ch)*512;
                gload16(gk + lane*8, (const char*)&Ksm[b][0] + (size_t)ch*1024);
            } else {
                const int cv = ch - 8;                 // dt = cv>>1, kt2 = cv&1
                const unsigned short* gv = Vf + kBase
                    + (size_t)((cv >> 1)*32 + jt*2 + (cv & 1))*512;
                gload16(gv + lane*8, (const char*)&Vsm[b][0] + (size_t)cv*1024);
            }
        }
    };

    stage(0, 0);                               // prologue: tile 0 into buf 0

    // Q fragments in registers (already scaled by QSCALE); overlap prologue.
    bf16x8 qh[2], ql[2];
    #pragma unroll
    for (int kt = 0; kt < 2; ++kt) {
        const unsigned short* p = Qf + qBase + ((size_t)mt0*2 + kt)*1024 + lane*8;
        qh[kt] = *(const bf16x8*)(p);
        ql[kt] = *(const bf16x8*)(p + 512);
    }

    // ones B-frag for the MFMA rowsum
    bf16x8 ones;
    #pragma unroll
    for (int i = 0; i < 8; ++i) ones[i] = (short)0x3F80;

    f32x4 out[4] = {};
    f32x4 lacc = {};
    float m_run[4];
    #pragma unroll
    for (int r = 0; r < 4; ++r) m_run[r] = -INFINITY;

    unsigned short* Pw = Psm + wid * 1024;

    __syncthreads();                           // prologue stage complete

    for (int jt = 0; jt < 16; ++jt) {
        const int cur = jt & 1;
        if (jt + 1 < 16) stage(cur ^ 1, jt + 1);   // prefetch next tile (hidden)

        // S = Q K^T, split-2 (K hi only)
        f32x4 s[4] = {};
        #pragma unroll
        for (int jn = 0; jn < 4; ++jn)
            #pragma unroll
            for (int kt = 0; kt < 2; ++kt) {
                const bf16x8 kh = *(const bf16x8*)(&Ksm[cur][0] + (jn*2 + kt)*512 + lane*8);
                s[jn] = MFMA16(qh[kt], kh, s[jn]);
                s[jn] = MFMA16(ql[kt], kh, s[jn]);
            }

        // defer-max: in-lane partial max -> wave-uniform skip predicate
        float mx[4];
        int ok = 1;
        #pragma unroll
        for (int r = 0; r < 4; ++r) {
            const float v = fmaxf(fmaxf(s[0][r], s[1][r]), fmaxf(s[2][r], s[3][r]));
            mx[r] = v;
            ok &= (v <= m_run[r] + 8.0f);
        }
        if (!__all(ok)) {
            float alf[4];
            #pragma unroll
            for (int r = 0; r < 4; ++r) {
                float v = mx[r];
                #pragma unroll
                for (int msk = 1; msk < 16; msk <<= 1)
                    v = fmaxf(v, __shfl_xor(v, msk));
                const float mn = fmaxf(m_run[r], v);
                alf[r] = exp2_fast(m_run[r] - mn);
                m_run[r] = mn;
            }
            #pragma unroll
            for (int dt = 0; dt < 4; ++dt)
                #pragma unroll
                for (int r = 0; r < 4; ++r)
                    out[dt][r] *= alf[r];
            #pragma unroll
            for (int r = 0; r < 4; ++r)
                lacc[r] *= alf[r];
        }

        // P = exp2(s - m) -> bf16-hi into swizzled A-frag LDS (wave-local)
        #pragma unroll
        for (int r = 0; r < 4; ++r) {
            const float mb_ = m_run[r];
            const int tl   = qrow0 + r + (colg << 4);
            const int idxb = ((tl << 3) | slot) ^ (tl & 0x18);
            #pragma unroll
            for (int jn = 0; jn < 4; ++jn)
                Pw[(jn >> 1)*512 + idxb + ((jn & 1) << 8)]
                    = f2bf(exp2_fast(s[jn][r] - mb_));
        }

        // PV + MFMA rowsum: read P back as bf16x8 A-frags (wave-local)
        const int rdswz = (lane*8) ^ (lane & 0x18);
        #pragma unroll
        for (int kt2 = 0; kt2 < 2; ++kt2) {
            const bf16x8 pa = *(const bf16x8*)(Pw + kt2*512 + rdswz);
            #pragma unroll
            for (int dt = 0; dt < 4; ++dt) {
                const bf16x8 vh = *(const bf16x8*)(&Vsm[cur][0] + (dt*2 + kt2)*512 + lane*8);
                out[dt] = MFMA16(pa, vh, out[dt]);
            }
            lacc = MFMA16(pa, ones, lacc);
        }

        __syncthreads();   // next tile staged by ALL waves; this tile's reads done
    }

    // epilogue: ctx / l  ->  proj-GEMM A-fragments (full hi+lo)
    const int b = bh / NHEADS, h = bh % NHEADS;
    #pragma unroll
    for (int r = 0; r < 4; ++r) {
        const float inv = 1.0f / lacc[r];
        const int sq = mt0*16 + qrow0 + r;
        const int mrow = b*SEQ + sq;
        #pragma unroll
        for (int dt = 0; dt < 4; ++dt) {
            const int c = h*64 + dt*16 + (lane & 15);
            const float val = out[dt][r] * inv;
            unsigned short hi, lo; split2(val, hi, lo);
            unsigned short* p = Cf + ((size_t)(mrow >> 4)*KT_D + (c >> 5))*1024
                              + ((mrow & 15) + (((c & 31) >> 3) << 4))*8 + (c & 7);
            p[0]   = hi;
            p[512] = lo;
        }
    }
}

// ---------------------------------------------------------------------------
extern "C" void kernel_launch(void* const* d_in, const int* in_sizes, int n_in,
                              void* d_out, int out_size, void* d_ws, size_t ws_size,
                              hipStream_t stream)
{
    const float* x      = (const float*)d_in[0];
    const float* w_qkv  = (const float*)d_in[1];
    const float* b_qkv  = (const float*)d_in[2];
    const float* w_proj = (const float*)d_in[3];
    const float* b_proj = (const float*)d_in[4];
    float* out = (float*)d_out;

    unsigned short* ws = (unsigned short*)d_ws;
    unsigned short* Xf = ws;                    // 12288 sub * 512    =  6,291,456
    unsigned short* Wq = Xf + 6291456;          // 3456 sub * 1024    =  3,538,944
    unsigned short* Wp = Wq + 3538944;          // 1152 sub * 1024    =  1,179,648
    unsigned short* Qf = Wp + 1179648;          // 96 * 131072        = 12,582,912
    unsigned short* Kf = Qf + 12582912;         // 96 * 65536         =  6,291,456
    unsigned short* Vf = Kf + 6291456;          // 96 * 65536         =  6,291,456
    unsigned short* Cf = Vf + 6291456;          // 12288 sub * 1024   = 12,582,912
    // total ~49.7M ushorts = ~95 MB of d_ws

    convert_a<<<dim3(3072), 256, 0, stream>>>(x, Xf, 786432);
    convert_b<<<dim3(864),  256, 0, stream>>>(w_qkv, Wq, QKV_COLS, 221184);
    convert_b<<<dim3(288),  256, 0, stream>>>(w_proj, Wp, D_MODEL, 73728);

    gemm_frag<0><<<dim3(2304), 256, 0, stream>>>(Xf, Wq, b_qkv, nullptr, Qf, Kf, Vf);
    attn_frag<<<dim3(768), 512, 0, stream>>>(Qf, Kf, Vf, Cf);
    gemm_frag<1><<<dim3(768), 256, 0, stream>>>(Cf, Wp, b_proj, out,
                                                nullptr, nullptr, nullptr);
}

// Round 12
// 177.903 us; speedup vs baseline: 1.3578x; 1.0062x over previous
//
#include <hip/hip_runtime.h>
#include <math.h>

#define D_MODEL 768
#define NHEADS  12
#define HDIM    64
#define SEQ     1024
#define BATCH   8
#define NBH     (BATCH*NHEADS)          // 96
#define M_TOTAL (BATCH*SEQ)             // 8192
#define KT_D    (D_MODEL/32)            // 24
#define QKV_COLS (3*D_MODEL)            // 2304

typedef __attribute__((ext_vector_type(8))) short bf16x8;
typedef __attribute__((ext_vector_type(4))) float f32x4;

#define MFMA16(a,b,c) __builtin_amdgcn_mfma_f32_16x16x32_bf16((a),(b),(c),0,0,0)

// Q pre-scale: 1/sqrt(64) * log2(e) so softmax runs in exp2 domain
#define QSCALE 0.18033688011112042f

// ---- helpers ----------------------------------------------------------------
__device__ inline unsigned short f2bf(float f) {
    unsigned u = __float_as_uint(f);
    u += 0x7FFFu + ((u >> 16) & 1u);
    return (unsigned short)(u >> 16);
}
__device__ inline float bf2f(unsigned short h) {
    return __uint_as_float(((unsigned)h) << 16);
}
__device__ inline void split2(float x, unsigned short& hi, unsigned short& lo) {
    hi = f2bf(x);
    lo = f2bf(x - bf2f(hi));
}
__device__ inline void gload16(const void* g, const void* l) {
    __builtin_amdgcn_global_load_lds(
        (const __attribute__((address_space(1))) unsigned*)g,
        (__attribute__((address_space(3))) unsigned*)l, 16, 0, 0);
}
__device__ inline float exp2_fast(float x) {
#if __has_builtin(__builtin_amdgcn_exp2f)
    return __builtin_amdgcn_exp2f(x);
#else
    float r; asm("v_exp_f32 %0, %1" : "=v"(r) : "v"(x)); return r;
#endif
}

// Fragment containers:
//  full subtile (hi+lo): 1024 ushorts (A-frag: lane=(row%16)+((k%32)/8)*16, slot=k%8)
//  hi-only subtile:       512 ushorts

// ---- convert x (fp32 [M][K]) -> A-fragments, HI-ONLY (gemm0 is split-2) ------
__global__ __launch_bounds__(256)
void convert_a(const float* __restrict__ src, unsigned short* __restrict__ dst,
               int total)
{
    const int gid = blockIdx.x * 256 + threadIdx.x;
    if (gid >= total) return;
    const int lane = gid & 63;
    const int sub  = gid >> 6;
    const int kt = sub % KT_D;
    const int mt = sub / KT_D;
    const float* s = src + (size_t)(mt*16 + (lane & 15)) * D_MODEL + kt*32 + (lane >> 4)*8;
    float4 v0 = *(const float4*)(s);
    float4 v1 = *(const float4*)(s + 4);
    float vv[8] = {v0.x, v0.y, v0.z, v0.w, v1.x, v1.y, v1.z, v1.w};
    union { unsigned short u[8]; bf16x8 v; } H;
    #pragma unroll
    for (int i = 0; i < 8; ++i) H.u[i] = f2bf(vv[i]);
    *(bf16x8*)(dst + (size_t)sub * 512 + lane * 8) = H.v;
}

// ---- convert weights (fp32 [K][N]) -> B-fragments, full hi+lo ----------------
__global__ __launch_bounds__(256)
void convert_b(const float* __restrict__ src, unsigned short* __restrict__ dst,
               int ldN, int total)
{
    const int gid = blockIdx.x * 256 + threadIdx.x;
    if (gid >= total) return;
    const int lane = gid & 63;
    const int sub  = gid >> 6;
    const int kt = sub % KT_D;
    const int nt = sub / KT_D;
    const int n  = nt*16 + (lane & 15);
    const int k0 = kt*32 + (lane >> 4)*8;
    const float* s = src + (size_t)k0 * ldN + n;
    union { unsigned short u[8]; bf16x8 v; } H, L;
    #pragma unroll
    for (int i = 0; i < 8; ++i) split2(s[(size_t)i * ldN], H.u[i], L.u[i]);
    unsigned short* d = dst + (size_t)sub * 1024 + lane * 8;
    *(bf16x8*)(d)       = H.v;
    *(bf16x8*)(d + 512) = L.v;
}

// ---- fragment GEMM, wave tile 64x32 (acc 8 f32x4, ~76 unified regs, no spill)
// MODE 0: 8 waves (2x4), 128x128 block tile, A hi-only split-2. 24KB staged/kt
//         per 128x128 output (vs 32KB for two 128x64 blocks) and half the
//         barrier events per CU. __launch_bounds__(512,4) -> 16 waves/CU.
//         Epilogue scatters Q(full)/K(hi)/V(hi) fragments.
// MODE 1: 4 waves (2x2), 128x64 tile, A full split-3; fp32 out + bias.
// Simple stage->sync->compute structure; inter-block TLP hides the drain (m114).
// 1-D grid, XCD swizzle: mb=(bid&7)*8+((bid>>3)&7), nb=bid>>6.
template<int MODE>
__global__ __launch_bounds__(MODE == 0 ? 512 : 256, 4)
void gemm_frag(const unsigned short* __restrict__ Af,
               const unsigned short* __restrict__ Bf,
               const float* __restrict__ bias,
               float* __restrict__ outF,
               unsigned short* __restrict__ outQ,
               unsigned short* __restrict__ outK,
               unsigned short* __restrict__ outV)
{
    constexpr int NW     = (MODE == 0) ? 8 : 4;     // waves per block
    constexpr int NSUB_N = (MODE == 0) ? 8 : 4;     // B subtiles per block
    constexpr int ACH    = (MODE == 0) ? 8 : 16;    // A 1KB-chunks per kt
    constexpr int NCH    = ACH + 2 * NSUB_N;        // total 1KB chunks (24 both)
    __shared__ unsigned short Asm[ACH * 512];
    __shared__ unsigned short Bsm[2 * NSUB_N * 512];
    const int t = threadIdx.x, lane = t & 63, wid = t >> 6;
    const int wr = (MODE == 0) ? (wid >> 2) : (wid >> 1);
    const int wc = (MODE == 0) ? (wid & 3)  : (wid & 1);
    const int bid = blockIdx.x;
    const int mb = (bid & 7) * 8 + ((bid >> 3) & 7);
    const int nb = bid >> 6;

    f32x4 acc[4][2] = {};

    for (int kt = 0; kt < KT_D; ++kt) {
        __syncthreads();                       // prior LDS reads done
        // stage: NCH 1KB chunks, NCH/NW per wave
        #pragma unroll
        for (int i = 0; i < NCH/NW; ++i) {
            const int c = wid * (NCH/NW) + i;
            const unsigned short* g;
            if (c < ACH) {
                if (MODE == 0)   // A hi-only: subtile c
                    g = Af + ((size_t)(mb*8 + c)*KT_D + kt)*512 + lane*8;
                else             // A full: subtile c>>1, plane c&1
                    g = Af + ((size_t)(mb*8 + (c >> 1))*KT_D + kt)*1024 + (c & 1)*512 + lane*8;
                gload16(g, (const char*)Asm + (size_t)c*1024);
            } else {
                const int j = c - ACH;         // B: subtile j>>1, plane j&1
                g = Bf + ((size_t)(nb*NSUB_N + (j >> 1))*KT_D + kt)*1024 + (j & 1)*512 + lane*8;
                gload16(g, (const char*)Bsm + (size_t)j*1024);
            }
        }
        __syncthreads();                       // staging complete (vmcnt drained)

        bf16x8 bh[2], bl[2];
        #pragma unroll
        for (int n = 0; n < 2; ++n) {
            bh[n] = *(const bf16x8*)(Bsm + (wc*2 + n)*1024 + lane*8);
            bl[n] = *(const bf16x8*)(Bsm + (wc*2 + n)*1024 + 512 + lane*8);
        }
        if (MODE == 0) {
            bf16x8 ah[4];
            #pragma unroll
            for (int m = 0; m < 4; ++m)
                ah[m] = *(const bf16x8*)(Asm + (wr*4 + m)*512 + lane*8);
            #pragma unroll
            for (int m = 0; m < 4; ++m)
                #pragma unroll
                for (int n = 0; n < 2; ++n) {
                    acc[m][n] = MFMA16(ah[m], bh[n], acc[m][n]);
                    acc[m][n] = MFMA16(ah[m], bl[n], acc[m][n]);
                }
        } else {
            bf16x8 ah[4], al[4];
            #pragma unroll
            for (int m = 0; m < 4; ++m) {
                ah[m] = *(const bf16x8*)(Asm + (wr*4 + m)*1024 + lane*8);
                al[m] = *(const bf16x8*)(Asm + (wr*4 + m)*1024 + 512 + lane*8);
            }
            #pragma unroll
            for (int m = 0; m < 4; ++m)
                #pragma unroll
                for (int n = 0; n < 2; ++n) {
                    acc[m][n] = MFMA16(ah[m], bh[n], acc[m][n]);
                    acc[m][n] = MFMA16(ah[m], bl[n], acc[m][n]);
                    acc[m][n] = MFMA16(al[m], bh[n], acc[m][n]);
                }
        }
    }

    const int rowW = mb*128 + wr*64;
    const int colW = nb*(NSUB_N*16) + wc*32;
    if (MODE == 1) {
        #pragma unroll
        for (int m = 0; m < 4; ++m)
            #pragma unroll
            for (int n = 0; n < 2; ++n) {
                const int col = colW + n*16 + (lane & 15);
                const float bv = bias[col];
                #pragma unroll
                for (int r = 0; r < 4; ++r) {
                    const int row = rowW + m*16 + (lane >> 4)*4 + r;
                    outF[(size_t)row * D_MODEL + col] = acc[m][n][r] + bv;
                }
            }
    } else {
        // wave-uniform (which, head): colW..colW+31 stays inside one head (64-wide)
        const int which = colW / D_MODEL;
        const int h     = (colW % D_MODEL) >> 6;
        #pragma unroll
        for (int m = 0; m < 4; ++m)
            #pragma unroll
            for (int n = 0; n < 2; ++n) {
                const int col = colW + n*16 + (lane & 15);
                const int d = col & 63;
                const float bv = bias[col];
                #pragma unroll
                for (int r = 0; r < 4; ++r) {
                    const int row = rowW + m*16 + (lane >> 4)*4 + r;
                    const int b = row >> 10, sq = row & 1023;
                    float val = acc[m][n][r] + bv;
                    if (which == 0) {                    // Q: full hi+lo, pre-scaled
                        val *= QSCALE;
                        const int sub = (sq >> 4)*2 + (d >> 5);
                        const int lp  = (sq & 15) + (((d & 31) >> 3) << 4);
                        unsigned short hi, lo; split2(val, hi, lo);
                        unsigned short* p = outQ + (size_t)(b*NHEADS + h)*131072
                                          + (size_t)sub*1024 + lp*8 + (d & 7);
                        p[0]   = hi;
                        p[512] = lo;
                    } else if (which == 1) {             // K: hi only
                        const int sub = (sq >> 4)*2 + (d >> 5);
                        const int lp  = (sq & 15) + (((d & 31) >> 3) << 4);
                        outK[(size_t)(b*NHEADS + h)*65536
                             + (size_t)sub*512 + lp*8 + (d & 7)] = f2bf(val);
                    } else {                             // V: hi only (B-frag)
                        const int sub = (d >> 4)*32 + (sq >> 5);
                        const int lp  = (d & 15) + (((sq & 31) >> 3) << 4);
                        outV[(size_t)(b*NHEADS + h)*65536
                             + (size_t)sub*512 + lp*8 + (sq & 7)] = f2bf(val);
                    }
                }
            }
    }
}

// ---- flash attention: 8 waves x 16 q-rows (1 m-subtile/wave), KV tiles of 64 -
// dbuf staging; K,V hi-only; QK split-2; PV hi-only; MFMA-ones rowsum;
// defer-max THR=8; exp2 domain. 24 waves/CU.
__global__ __launch_bounds__(512, 6)
void attn_frag(const unsigned short* __restrict__ Qf,
               const unsigned short* __restrict__ Kf,
               const unsigned short* __restrict__ Vf,
               unsigned short* __restrict__ Cf)
{
    __shared__ unsigned short Ksm[2][8 * 512];   // dbuf: 4 jn x 2 kt hi subtiles
    __shared__ unsigned short Vsm[2][8 * 512];   // dbuf: 4 dt x 2 kt2 hi subtiles
    __shared__ unsigned short Psm[8 * 1024];     // per-wave P: 2 subtiles x 512 bf16

    const int t = threadIdx.x, lane = t & 63, wid = t >> 6;   // wid 0..7
    // XCD swizzle: all 8 q-blocks of one (b,h) land on the same XCD
    const int bid = blockIdx.x;
    const int qb  = (bid >> 3) & 7;
    const int bh  = (bid & 7) * 12 + (bid >> 6);
    const int mt0 = qb*8 + wid;                // wave's q-subtile (of 64)
    const size_t qBase = (size_t)bh * 131072;
    const size_t kBase = (size_t)bh * 65536;

    const int slot  = lane & 7;
    const int colg  = (lane & 15) >> 3;        // 0/1
    const int qrow0 = (lane >> 4) * 4;         // 0,4,8,12

    // stage K/V hi subtiles of kv-tile jt into buffer b (2 chunks per wave)
    auto stage = [&](int b, int jt) {
        #pragma unroll
        for (int i = 0; i < 2; ++i) {
            const int ch = wid*2 + i;
            if (ch < 8) {
                const unsigned short* gk = Kf + kBase + (size_t)(jt*8 + ch)*512;
                gload16(gk + lane*8, (const char*)&Ksm[b][0] + (size_t)ch*1024);
            } else {
                const int cv = ch - 8;                 // dt = cv>>1, kt2 = cv&1
                const unsigned short* gv = Vf + kBase
                    + (size_t)((cv >> 1)*32 + jt*2 + (cv & 1))*512;
                gload16(gv + lane*8, (const char*)&Vsm[b][0] + (size_t)cv*1024);
            }
        }
    };

    stage(0, 0);                               // prologue: tile 0 into buf 0

    // Q fragments in registers (already scaled by QSCALE); overlap prologue.
    bf16x8 qh[2], ql[2];
    #pragma unroll
    for (int kt = 0; kt < 2; ++kt) {
        const unsigned short* p = Qf + qBase + ((size_t)mt0*2 + kt)*1024 + lane*8;
        qh[kt] = *(const bf16x8*)(p);
        ql[kt] = *(const bf16x8*)(p + 512);
    }

    // ones B-frag for the MFMA rowsum
    bf16x8 ones;
    #pragma unroll
    for (int i = 0; i < 8; ++i) ones[i] = (short)0x3F80;

    f32x4 out[4] = {};
    f32x4 lacc = {};
    float m_run[4];
    #pragma unroll
    for (int r = 0; r < 4; ++r) m_run[r] = -INFINITY;

    unsigned short* Pw = Psm + wid * 1024;

    __syncthreads();                           // prologue stage complete

    for (int jt = 0; jt < 16; ++jt) {
        const int cur = jt & 1;
        if (jt + 1 < 16) stage(cur ^ 1, jt + 1);   // prefetch next tile (hidden)

        // S = Q K^T, split-2 (K hi only)
        f32x4 s[4] = {};
        #pragma unroll
        for (int jn = 0; jn < 4; ++jn)
            #pragma unroll
            for (int kt = 0; kt < 2; ++kt) {
                const bf16x8 kh = *(const bf16x8*)(&Ksm[cur][0] + (jn*2 + kt)*512 + lane*8);
                s[jn] = MFMA16(qh[kt], kh, s[jn]);
                s[jn] = MFMA16(ql[kt], kh, s[jn]);
            }

        // defer-max: in-lane partial max -> wave-uniform skip predicate
        float mx[4];
        int ok = 1;
        #pragma unroll
        for (int r = 0; r < 4; ++r) {
            const float v = fmaxf(fmaxf(s[0][r], s[1][r]), fmaxf(s[2][r], s[3][r]));
            mx[r] = v;
            ok &= (v <= m_run[r] + 8.0f);
        }
        if (!__all(ok)) {
            float alf[4];
            #pragma unroll
            for (int r = 0; r < 4; ++r) {
                float v = mx[r];
                #pragma unroll
                for (int msk = 1; msk < 16; msk <<= 1)
                    v = fmaxf(v, __shfl_xor(v, msk));
                const float mn = fmaxf(m_run[r], v);
                alf[r] = exp2_fast(m_run[r] - mn);
                m_run[r] = mn;
            }
            #pragma unroll
            for (int dt = 0; dt < 4; ++dt)
                #pragma unroll
                for (int r = 0; r < 4; ++r)
                    out[dt][r] *= alf[r];
            #pragma unroll
            for (int r = 0; r < 4; ++r)
                lacc[r] *= alf[r];
        }

        // P = exp2(s - m) -> bf16-hi into swizzled A-frag LDS (wave-local)
        #pragma unroll
        for (int r = 0; r < 4; ++r) {
            const float mb_ = m_run[r];
            const int tl   = qrow0 + r + (colg << 4);
            const int idxb = ((tl << 3) | slot) ^ (tl & 0x18);
            #pragma unroll
            for (int jn = 0; jn < 4; ++jn)
                Pw[(jn >> 1)*512 + idxb + ((jn & 1) << 8)]
                    = f2bf(exp2_fast(s[jn][r] - mb_));
        }

        // PV + MFMA rowsum: read P back as bf16x8 A-frags (wave-local)
        const int rdswz = (lane*8) ^ (lane & 0x18);
        #pragma unroll
        for (int kt2 = 0; kt2 < 2; ++kt2) {
            const bf16x8 pa = *(const bf16x8*)(Pw + kt2*512 + rdswz);
            #pragma unroll
            for (int dt = 0; dt < 4; ++dt) {
                const bf16x8 vh = *(const bf16x8*)(&Vsm[cur][0] + (dt*2 + kt2)*512 + lane*8);
                out[dt] = MFMA16(pa, vh, out[dt]);
            }
            lacc = MFMA16(pa, ones, lacc);
        }

        __syncthreads();   // next tile staged by ALL waves; this tile's reads done
    }

    // epilogue: ctx / l  ->  proj-GEMM A-fragments (full hi+lo)
    const int b = bh / NHEADS, h = bh % NHEADS;
    #pragma unroll
    for (int r = 0; r < 4; ++r) {
        const float inv = 1.0f / lacc[r];
        const int sq = mt0*16 + qrow0 + r;
        const int mrow = b*SEQ + sq;
        #pragma unroll
        for (int dt = 0; dt < 4; ++dt) {
            const int c = h*64 + dt*16 + (lane & 15);
            const float val = out[dt][r] * inv;
            unsigned short hi, lo; split2(val, hi, lo);
            unsigned short* p = Cf + ((size_t)(mrow >> 4)*KT_D + (c >> 5))*1024
                              + ((mrow & 15) + (((c & 31) >> 3) << 4))*8 + (c & 7);
            p[0]   = hi;
            p[512] = lo;
        }
    }
}

// ---------------------------------------------------------------------------
extern "C" void kernel_launch(void* const* d_in, const int* in_sizes, int n_in,
                              void* d_out, int out_size, void* d_ws, size_t ws_size,
                              hipStream_t stream)
{
    const float* x      = (const float*)d_in[0];
    const float* w_qkv  = (const float*)d_in[1];
    const float* b_qkv  = (const float*)d_in[2];
    const float* w_proj = (const float*)d_in[3];
    const float* b_proj = (const float*)d_in[4];
    float* out = (float*)d_out;

    unsigned short* ws = (unsigned short*)d_ws;
    unsigned short* Xf = ws;                    // 12288 sub * 512    =  6,291,456
    unsigned short* Wq = Xf + 6291456;          // 3456 sub * 1024    =  3,538,944
    unsigned short* Wp = Wq + 3538944;          // 1152 sub * 1024    =  1,179,648
    unsigned short* Qf = Wp + 1179648;          // 96 * 131072        = 12,582,912
    unsigned short* Kf = Qf + 12582912;         // 96 * 65536         =  6,291,456
    unsigned short* Vf = Kf + 6291456;          // 96 * 65536         =  6,291,456
    unsigned short* Cf = Vf + 6291456;          // 12288 sub * 1024   = 12,582,912
    // total ~49.7M ushorts = ~95 MB of d_ws

    convert_a<<<dim3(3072), 256, 0, stream>>>(x, Xf, 786432);
    convert_b<<<dim3(864),  256, 0, stream>>>(w_qkv, Wq, QKV_COLS, 221184);
    convert_b<<<dim3(288),  256, 0, stream>>>(w_proj, Wp, D_MODEL, 73728);

    // gemm0: 128x128 tiles -> grid 64 x 18 = 1152 (mb-swizzled, nb = bid>>6)
    gemm_frag<0><<<dim3(1152), 512, 0, stream>>>(Xf, Wq, b_qkv, nullptr, Qf, Kf, Vf);
    attn_frag<<<dim3(768), 512, 0, stream>>>(Qf, Kf, Vf, Cf);
    gemm_frag<1><<<dim3(768), 256, 0, stream>>>(Cf, Wp, b_proj, out,
                                                nullptr, nullptr, nullptr);
}

// Round 13
// 171.574 us; speedup vs baseline: 1.4078x; 1.0369x over previous
//
#include <hip/hip_runtime.h>
#include <math.h>

#define D_MODEL 768
#define NHEADS  12
#define HDIM    64
#define SEQ     1024
#define BATCH   8
#define NBH     (BATCH*NHEADS)          // 96
#define M_TOTAL (BATCH*SEQ)             // 8192
#define KT_D    (D_MODEL/32)            // 24
#define QKV_COLS (3*D_MODEL)            // 2304

typedef __attribute__((ext_vector_type(8))) short bf16x8;
typedef __attribute__((ext_vector_type(4))) float f32x4;

#define MFMA16(a,b,c) __builtin_amdgcn_mfma_f32_16x16x32_bf16((a),(b),(c),0,0,0)

// Q pre-scale: 1/sqrt(64) * log2(e) so softmax runs in exp2 domain
#define QSCALE 0.18033688011112042f

// ---- helpers ----------------------------------------------------------------
__device__ inline unsigned short f2bf(float f) {
    unsigned u = __float_as_uint(f);
    u += 0x7FFFu + ((u >> 16) & 1u);
    return (unsigned short)(u >> 16);
}
__device__ inline float bf2f(unsigned short h) {
    return __uint_as_float(((unsigned)h) << 16);
}
__device__ inline void split2(float x, unsigned short& hi, unsigned short& lo) {
    hi = f2bf(x);
    lo = f2bf(x - bf2f(hi));
}
__device__ inline void gload16(const void* g, const void* l) {
    __builtin_amdgcn_global_load_lds(
        (const __attribute__((address_space(1))) unsigned*)g,
        (__attribute__((address_space(3))) unsigned*)l, 16, 0, 0);
}
__device__ inline float exp2_fast(float x) {
#if __has_builtin(__builtin_amdgcn_exp2f)
    return __builtin_amdgcn_exp2f(x);
#else
    float r; asm("v_exp_f32 %0, %1" : "=v"(r) : "v"(x)); return r;
#endif
}

// Fragment containers:
//  full subtile (hi+lo): 1024 ushorts (A-frag: lane=(row%16)+((k%32)/8)*16, slot=k%8)
//  hi-only subtile:       512 ushorts

// ---- convert x (fp32 [M][K]) -> A-fragments, HI-ONLY ------------------------
__global__ __launch_bounds__(256)
void convert_a(const float* __restrict__ src, unsigned short* __restrict__ dst,
               int total)
{
    const int gid = blockIdx.x * 256 + threadIdx.x;
    if (gid >= total) return;
    const int lane = gid & 63;
    const int sub  = gid >> 6;
    const int kt = sub % KT_D;
    const int mt = sub / KT_D;
    const float* s = src + (size_t)(mt*16 + (lane & 15)) * D_MODEL + kt*32 + (lane >> 4)*8;
    float4 v0 = *(const float4*)(s);
    float4 v1 = *(const float4*)(s + 4);
    float vv[8] = {v0.x, v0.y, v0.z, v0.w, v1.x, v1.y, v1.z, v1.w};
    union { unsigned short u[8]; bf16x8 v; } H;
    #pragma unroll
    for (int i = 0; i < 8; ++i) H.u[i] = f2bf(vv[i]);
    *(bf16x8*)(dst + (size_t)sub * 512 + lane * 8) = H.v;
}

// ---- convert weights (fp32 [K][N]) -> B-fragments, full hi+lo ----------------
__global__ __launch_bounds__(256)
void convert_b(const float* __restrict__ src, unsigned short* __restrict__ dst,
               int ldN, int total)
{
    const int gid = blockIdx.x * 256 + threadIdx.x;
    if (gid >= total) return;
    const int lane = gid & 63;
    const int sub  = gid >> 6;
    const int kt = sub % KT_D;
    const int nt = sub / KT_D;
    const int n  = nt*16 + (lane & 15);
    const int k0 = kt*32 + (lane >> 4)*8;
    const float* s = src + (size_t)k0 * ldN + n;
    union { unsigned short u[8]; bf16x8 v; } H, L;
    #pragma unroll
    for (int i = 0; i < 8; ++i) split2(s[(size_t)i * ldN], H.u[i], L.u[i]);
    unsigned short* d = dst + (size_t)sub * 1024 + lane * 8;
    *(bf16x8*)(d)       = H.v;
    *(bf16x8*)(d + 512) = L.v;
}

// ---- fragment GEMM, A hi-only split-2 everywhere (ah*bh + ah*bl) -------------
// Occupancy is reg-capped at 4 waves/SIMD (acc+operands ~72 regs; forcing <=64
// spills — round 10). Remaining levers: fewer sync events (MODE0 K-pair) and
// less work (split-2 both GEMMs).
// MODE 0: 8 waves (2x4), 128x128 tile, K-PAIR stepping: stage 2 K-steps per
//         barrier pair (24->12 drains, each amortized over 2x compute).
//         LDS 48KB, 2 blocks/CU (reg-capped anyway). Scatters Q/K/V frags.
// MODE 1: 4 waves (2x2), 128x64 tile, single-kt; fp32 out + bias.
// 1-D grid, XCD swizzle: mb=(bid&7)*8+((bid>>3)&7), nb=bid>>6.
template<int MODE>
__global__ __launch_bounds__(MODE == 0 ? 512 : 256, 4)
void gemm_frag(const unsigned short* __restrict__ Af,
               const unsigned short* __restrict__ Bf,
               const float* __restrict__ bias,
               float* __restrict__ outF,
               unsigned short* __restrict__ outQ,
               unsigned short* __restrict__ outK,
               unsigned short* __restrict__ outV)
{
    constexpr int KPAIR  = (MODE == 0) ? 2 : 1;     // K-steps per barrier pair
    constexpr int NW     = (MODE == 0) ? 8 : 4;     // waves per block
    constexpr int NSUB_N = (MODE == 0) ? 8 : 4;     // B subtiles per block
    constexpr int ACH    = 8;                       // A hi 1KB-chunks per kt
    constexpr int NCH1   = ACH + 2 * NSUB_N;        // chunks per kt (24 / 16)
    constexpr int NCH    = NCH1 * KPAIR;            // chunks per iter (48 / 16)
    __shared__ unsigned short Asm[KPAIR][ACH * 512];
    __shared__ unsigned short Bsm[KPAIR][NSUB_N * 1024];
    const int t = threadIdx.x, lane = t & 63, wid = t >> 6;
    const int wr = (MODE == 0) ? (wid >> 2) : (wid >> 1);
    const int wc = (MODE == 0) ? (wid & 3)  : (wid & 1);
    const int bid = blockIdx.x;
    const int mb = (bid & 7) * 8 + ((bid >> 3) & 7);
    const int nb = bid >> 6;

    f32x4 acc[4][2] = {};

    for (int ktp = 0; ktp < KT_D / KPAIR; ++ktp) {
        __syncthreads();                       // prior LDS reads done
        // stage NCH 1KB chunks, NCH/NW per wave
        #pragma unroll
        for (int i = 0; i < NCH/NW; ++i) {
            const int c    = wid * (NCH/NW) + i;
            const int half = c / NCH1;
            const int cc   = c % NCH1;
            const int kt   = ktp * KPAIR + half;
            if (cc < ACH) {                    // A hi-only subtile cc
                const unsigned short* g =
                    Af + ((size_t)(mb*8 + cc)*KT_D + kt)*512 + lane*8;
                gload16(g, (const char*)&Asm[half][0] + (size_t)cc*1024);
            } else {                           // B subtile j>>1, plane j&1
                const int j = cc - ACH;
                const unsigned short* g =
                    Bf + ((size_t)(nb*NSUB_N + (j >> 1))*KT_D + kt)*1024 + (j & 1)*512 + lane*8;
                gload16(g, (const char*)&Bsm[half][0] + (size_t)j*1024);
            }
        }
        __syncthreads();                       // staging complete (vmcnt drained)

        #pragma unroll
        for (int half = 0; half < KPAIR; ++half) {
            bf16x8 bh[2], bl[2];
            #pragma unroll
            for (int n = 0; n < 2; ++n) {
                bh[n] = *(const bf16x8*)(&Bsm[half][0] + (wc*2 + n)*1024 + lane*8);
                bl[n] = *(const bf16x8*)(&Bsm[half][0] + (wc*2 + n)*1024 + 512 + lane*8);
            }
            bf16x8 ah[4];
            #pragma unroll
            for (int m = 0; m < 4; ++m)
                ah[m] = *(const bf16x8*)(&Asm[half][0] + (wr*4 + m)*512 + lane*8);
            #pragma unroll
            for (int m = 0; m < 4; ++m)
                #pragma unroll
                for (int n = 0; n < 2; ++n) {
                    acc[m][n] = MFMA16(ah[m], bh[n], acc[m][n]);
                    acc[m][n] = MFMA16(ah[m], bl[n], acc[m][n]);
                }
        }
    }

    const int rowW = mb*128 + wr*64;
    const int colW = nb*(NSUB_N*16) + wc*32;
    if (MODE == 1) {
        #pragma unroll
        for (int m = 0; m < 4; ++m)
            #pragma unroll
            for (int n = 0; n < 2; ++n) {
                const int col = colW + n*16 + (lane & 15);
                const float bv = bias[col];
                #pragma unroll
                for (int r = 0; r < 4; ++r) {
                    const int row = rowW + m*16 + (lane >> 4)*4 + r;
                    outF[(size_t)row * D_MODEL + col] = acc[m][n][r] + bv;
                }
            }
    } else {
        // wave-uniform (which, head): colW..colW+31 stays inside one head (64-wide)
        const int which = colW / D_MODEL;
        const int h     = (colW % D_MODEL) >> 6;
        #pragma unroll
        for (int m = 0; m < 4; ++m)
            #pragma unroll
            for (int n = 0; n < 2; ++n) {
                const int col = colW + n*16 + (lane & 15);
                const int d = col & 63;
                const float bv = bias[col];
                #pragma unroll
                for (int r = 0; r < 4; ++r) {
                    const int row = rowW + m*16 + (lane >> 4)*4 + r;
                    const int b = row >> 10, sq = row & 1023;
                    float val = acc[m][n][r] + bv;
                    if (which == 0) {                    // Q: full hi+lo, pre-scaled
                        val *= QSCALE;
                        const int sub = (sq >> 4)*2 + (d >> 5);
                        const int lp  = (sq & 15) + (((d & 31) >> 3) << 4);
                        unsigned short hi, lo; split2(val, hi, lo);
                        unsigned short* p = outQ + (size_t)(b*NHEADS + h)*131072
                                          + (size_t)sub*1024 + lp*8 + (d & 7);
                        p[0]   = hi;
                        p[512] = lo;
                    } else if (which == 1) {             // K: hi only
                        const int sub = (sq >> 4)*2 + (d >> 5);
                        const int lp  = (sq & 15) + (((d & 31) >> 3) << 4);
                        outK[(size_t)(b*NHEADS + h)*65536
                             + (size_t)sub*512 + lp*8 + (d & 7)] = f2bf(val);
                    } else {                             // V: hi only (B-frag)
                        const int sub = (d >> 4)*32 + (sq >> 5);
                        const int lp  = (d & 15) + (((sq & 31) >> 3) << 4);
                        outV[(size_t)(b*NHEADS + h)*65536
                             + (size_t)sub*512 + lp*8 + (sq & 7)] = f2bf(val);
                    }
                }
            }
    }
}

// ---- flash attention: 8 waves x 16 q-rows (1 m-subtile/wave), KV tiles of 64 -
// dbuf staging; K,V hi-only; QK split-2; PV hi-only; MFMA-ones rowsum;
// defer-max THR=8; exp2 domain. 24 waves/CU. Epilogue: hi-only Cf fragments.
__global__ __launch_bounds__(512, 6)
void attn_frag(const unsigned short* __restrict__ Qf,
               const unsigned short* __restrict__ Kf,
               const unsigned short* __restrict__ Vf,
               unsigned short* __restrict__ Cf)
{
    __shared__ unsigned short Ksm[2][8 * 512];   // dbuf: 4 jn x 2 kt hi subtiles
    __shared__ unsigned short Vsm[2][8 * 512];   // dbuf: 4 dt x 2 kt2 hi subtiles
    __shared__ unsigned short Psm[8 * 1024];     // per-wave P: 2 subtiles x 512 bf16

    const int t = threadIdx.x, lane = t & 63, wid = t >> 6;   // wid 0..7
    // XCD swizzle: all 8 q-blocks of one (b,h) land on the same XCD
    const int bid = blockIdx.x;
    const int qb  = (bid >> 3) & 7;
    const int bh  = (bid & 7) * 12 + (bid >> 6);
    const int mt0 = qb*8 + wid;                // wave's q-subtile (of 64)
    const size_t qBase = (size_t)bh * 131072;
    const size_t kBase = (size_t)bh * 65536;

    const int slot  = lane & 7;
    const int colg  = (lane & 15) >> 3;        // 0/1
    const int qrow0 = (lane >> 4) * 4;         // 0,4,8,12

    // stage K/V hi subtiles of kv-tile jt into buffer b (2 chunks per wave)
    auto stage = [&](int b, int jt) {
        #pragma unroll
        for (int i = 0; i < 2; ++i) {
            const int ch = wid*2 + i;
            if (ch < 8) {
                const unsigned short* gk = Kf + kBase + (size_t)(jt*8 + ch)*512;
                gload16(gk + lane*8, (const char*)&Ksm[b][0] + (size_t)ch*1024);
            } else {
                const int cv = ch - 8;                 // dt = cv>>1, kt2 = cv&1
                const unsigned short* gv = Vf + kBase
                    + (size_t)((cv >> 1)*32 + jt*2 + (cv & 1))*512;
                gload16(gv + lane*8, (const char*)&Vsm[b][0] + (size_t)cv*1024);
            }
        }
    };

    stage(0, 0);                               // prologue: tile 0 into buf 0

    // Q fragments in registers (already scaled by QSCALE); overlap prologue.
    bf16x8 qh[2], ql[2];
    #pragma unroll
    for (int kt = 0; kt < 2; ++kt) {
        const unsigned short* p = Qf + qBase + ((size_t)mt0*2 + kt)*1024 + lane*8;
        qh[kt] = *(const bf16x8*)(p);
        ql[kt] = *(const bf16x8*)(p + 512);
    }

    // ones B-frag for the MFMA rowsum
    bf16x8 ones;
    #pragma unroll
    for (int i = 0; i < 8; ++i) ones[i] = (short)0x3F80;

    f32x4 out[4] = {};
    f32x4 lacc = {};
    float m_run[4];
    #pragma unroll
    for (int r = 0; r < 4; ++r) m_run[r] = -INFINITY;

    unsigned short* Pw = Psm + wid * 1024;

    __syncthreads();                           // prologue stage complete

    for (int jt = 0; jt < 16; ++jt) {
        const int cur = jt & 1;
        if (jt + 1 < 16) stage(cur ^ 1, jt + 1);   // prefetch next tile (hidden)

        // S = Q K^T, split-2 (K hi only)
        f32x4 s[4] = {};
        #pragma unroll
        for (int jn = 0; jn < 4; ++jn)
            #pragma unroll
            for (int kt = 0; kt < 2; ++kt) {
                const bf16x8 kh = *(const bf16x8*)(&Ksm[cur][0] + (jn*2 + kt)*512 + lane*8);
                s[jn] = MFMA16(qh[kt], kh, s[jn]);
                s[jn] = MFMA16(ql[kt], kh, s[jn]);
            }

        // defer-max: in-lane partial max -> wave-uniform skip predicate
        float mx[4];
        int ok = 1;
        #pragma unroll
        for (int r = 0; r < 4; ++r) {
            const float v = fmaxf(fmaxf(s[0][r], s[1][r]), fmaxf(s[2][r], s[3][r]));
            mx[r] = v;
            ok &= (v <= m_run[r] + 8.0f);
        }
        if (!__all(ok)) {
            float alf[4];
            #pragma unroll
            for (int r = 0; r < 4; ++r) {
                float v = mx[r];
                #pragma unroll
                for (int msk = 1; msk < 16; msk <<= 1)
                    v = fmaxf(v, __shfl_xor(v, msk));
                const float mn = fmaxf(m_run[r], v);
                alf[r] = exp2_fast(m_run[r] - mn);
                m_run[r] = mn;
            }
            #pragma unroll
            for (int dt = 0; dt < 4; ++dt)
                #pragma unroll
                for (int r = 0; r < 4; ++r)
                    out[dt][r] *= alf[r];
            #pragma unroll
            for (int r = 0; r < 4; ++r)
                lacc[r] *= alf[r];
        }

        // P = exp2(s - m) -> bf16-hi into swizzled A-frag LDS (wave-local)
        #pragma unroll
        for (int r = 0; r < 4; ++r) {
            const float mb_ = m_run[r];
            const int tl   = qrow0 + r + (colg << 4);
            const int idxb = ((tl << 3) | slot) ^ (tl & 0x18);
            #pragma unroll
            for (int jn = 0; jn < 4; ++jn)
                Pw[(jn >> 1)*512 + idxb + ((jn & 1) << 8)]
                    = f2bf(exp2_fast(s[jn][r] - mb_));
        }

        // PV + MFMA rowsum: read P back as bf16x8 A-frags (wave-local)
        const int rdswz = (lane*8) ^ (lane & 0x18);
        #pragma unroll
        for (int kt2 = 0; kt2 < 2; ++kt2) {
            const bf16x8 pa = *(const bf16x8*)(Pw + kt2*512 + rdswz);
            #pragma unroll
            for (int dt = 0; dt < 4; ++dt) {
                const bf16x8 vh = *(const bf16x8*)(&Vsm[cur][0] + (dt*2 + kt2)*512 + lane*8);
                out[dt] = MFMA16(pa, vh, out[dt]);
            }
            lacc = MFMA16(pa, ones, lacc);
        }

        __syncthreads();   // next tile staged by ALL waves; this tile's reads done
    }

    // epilogue: ctx / l -> proj-GEMM A-fragments, HI-ONLY
    const int b = bh / NHEADS, h = bh % NHEADS;
    #pragma unroll
    for (int r = 0; r < 4; ++r) {
        const float inv = 1.0f / lacc[r];
        const int sq = mt0*16 + qrow0 + r;
        const int mrow = b*SEQ + sq;
        #pragma unroll
        for (int dt = 0; dt < 4; ++dt) {
            const int c = h*64 + dt*16 + (lane & 15);
            const float val = out[dt][r] * inv;
            Cf[((size_t)(mrow >> 4)*KT_D + (c >> 5))*512
               + ((mrow & 15) + (((c & 31) >> 3) << 4))*8 + (c & 7)] = f2bf(val);
        }
    }
}

// ---------------------------------------------------------------------------
extern "C" void kernel_launch(void* const* d_in, const int* in_sizes, int n_in,
                              void* d_out, int out_size, void* d_ws, size_t ws_size,
                              hipStream_t stream)
{
    const float* x      = (const float*)d_in[0];
    const float* w_qkv  = (const float*)d_in[1];
    const float* b_qkv  = (const float*)d_in[2];
    const float* w_proj = (const float*)d_in[3];
    const float* b_proj = (const float*)d_in[4];
    float* out = (float*)d_out;

    unsigned short* ws = (unsigned short*)d_ws;
    unsigned short* Xf = ws;                    // 12288 sub * 512    =  6,291,456
    unsigned short* Wq = Xf + 6291456;          // 3456 sub * 1024    =  3,538,944
    unsigned short* Wp = Wq + 3538944;          // 1152 sub * 1024    =  1,179,648
    unsigned short* Qf = Wp + 1179648;          // 96 * 131072        = 12,582,912
    unsigned short* Kf = Qf + 12582912;         // 96 * 65536         =  6,291,456
    unsigned short* Vf = Kf + 6291456;          // 96 * 65536         =  6,291,456
    unsigned short* Cf = Vf + 6291456;          // 12288 sub * 512    =  6,291,456
    // total ~43.4M ushorts = ~83 MB of d_ws

    convert_a<<<dim3(3072), 256, 0, stream>>>(x, Xf, 786432);
    convert_b<<<dim3(864),  256, 0, stream>>>(w_qkv, Wq, QKV_COLS, 221184);
    convert_b<<<dim3(288),  256, 0, stream>>>(w_proj, Wp, D_MODEL, 73728);

    // gemm0: 128x128 tiles -> grid 64 x 18 = 1152 (mb-swizzled, nb = bid>>6)
    gemm_frag<0><<<dim3(1152), 512, 0, stream>>>(Xf, Wq, b_qkv, nullptr, Qf, Kf, Vf);
    attn_frag<<<dim3(768), 512, 0, stream>>>(Qf, Kf, Vf, Cf);
    // gemm1: 128x64 tiles -> grid 64 x 12 = 768
    gemm_frag<1><<<dim3(768), 256, 0, stream>>>(Cf, Wp, b_proj, out,
                                                nullptr, nullptr, nullptr);
}

// Round 14
// 165.984 us; speedup vs baseline: 1.4553x; 1.0337x over previous
//
#include <hip/hip_runtime.h>
#include <math.h>

#define D_MODEL 768
#define NHEADS  12
#define HDIM    64
#define SEQ     1024
#define BATCH   8
#define NBH     (BATCH*NHEADS)          // 96
#define M_TOTAL (BATCH*SEQ)             // 8192
#define KT_D    (D_MODEL/32)            // 24
#define QKV_COLS (3*D_MODEL)            // 2304

typedef __attribute__((ext_vector_type(8))) short bf16x8;
typedef __attribute__((ext_vector_type(4))) float f32x4;

#define MFMA16(a,b,c) __builtin_amdgcn_mfma_f32_16x16x32_bf16((a),(b),(c),0,0,0)

// Q pre-scale: 1/sqrt(64) * log2(e) so softmax runs in exp2 domain
#define QSCALE 0.18033688011112042f

// ---- helpers ----------------------------------------------------------------
__device__ inline unsigned short f2bf(float f) {
    unsigned u = __float_as_uint(f);
    u += 0x7FFFu + ((u >> 16) & 1u);
    return (unsigned short)(u >> 16);
}
__device__ inline float bf2f(unsigned short h) {
    return __uint_as_float(((unsigned)h) << 16);
}
__device__ inline void split2(float x, unsigned short& hi, unsigned short& lo) {
    hi = f2bf(x);
    lo = f2bf(x - bf2f(hi));
}
__device__ inline void gload16(const void* g, const void* l) {
    __builtin_amdgcn_global_load_lds(
        (const __attribute__((address_space(1))) unsigned*)g,
        (__attribute__((address_space(3))) unsigned*)l, 16, 0, 0);
}
__device__ inline float exp2_fast(float x) {
#if __has_builtin(__builtin_amdgcn_exp2f)
    return __builtin_amdgcn_exp2f(x);
#else
    float r; asm("v_exp_f32 %0, %1" : "=v"(r) : "v"(x)); return r;
#endif
}

// Fragment containers:
//  full subtile (hi+lo): 1024 ushorts (A-frag: lane=(row%16)+((k%32)/8)*16, slot=k%8)
//  hi-only subtile:       512 ushorts

// ---- convert x (fp32 [M][K]) -> A-fragments, HI-ONLY ------------------------
__global__ __launch_bounds__(256)
void convert_a(const float* __restrict__ src, unsigned short* __restrict__ dst,
               int total)
{
    const int gid = blockIdx.x * 256 + threadIdx.x;
    if (gid >= total) return;
    const int lane = gid & 63;
    const int sub  = gid >> 6;
    const int kt = sub % KT_D;
    const int mt = sub / KT_D;
    const float* s = src + (size_t)(mt*16 + (lane & 15)) * D_MODEL + kt*32 + (lane >> 4)*8;
    float4 v0 = *(const float4*)(s);
    float4 v1 = *(const float4*)(s + 4);
    float vv[8] = {v0.x, v0.y, v0.z, v0.w, v1.x, v1.y, v1.z, v1.w};
    union { unsigned short u[8]; bf16x8 v; } H;
    #pragma unroll
    for (int i = 0; i < 8; ++i) H.u[i] = f2bf(vv[i]);
    *(bf16x8*)(dst + (size_t)sub * 512 + lane * 8) = H.v;
}

// ---- convert weights (fp32 [K][N]) -> B-fragments, full hi+lo ----------------
__global__ __launch_bounds__(256)
void convert_b(const float* __restrict__ src, unsigned short* __restrict__ dst,
               int ldN, int total)
{
    const int gid = blockIdx.x * 256 + threadIdx.x;
    if (gid >= total) return;
    const int lane = gid & 63;
    const int sub  = gid >> 6;
    const int kt = sub % KT_D;
    const int nt = sub / KT_D;
    const int n  = nt*16 + (lane & 15);
    const int k0 = kt*32 + (lane >> 4)*8;
    const float* s = src + (size_t)k0 * ldN + n;
    union { unsigned short u[8]; bf16x8 v; } H, L;
    #pragma unroll
    for (int i = 0; i < 8; ++i) split2(s[(size_t)i * ldN], H.u[i], L.u[i]);
    unsigned short* d = dst + (size_t)sub * 1024 + lane * 8;
    *(bf16x8*)(d)       = H.v;
    *(bf16x8*)(d + 512) = L.v;
}

// ---- fragment GEMM, A hi-only split-2 (ah*bh + ah*bl), single-kt staging -----
// Round-13 K-pair REVERTED: 48KB LDS + fatter addressing cut occupancy
// 49.7->33.8% and regressed 79.7->91.2us (m132 failure mode). This is the
// round-12 structure (79.7us @ 49.7% occ) with A hi-only in both modes.
// MODE 0: 8 waves (2x4), 128x128 tile, 24KB LDS; scatters Q/K/V fragments.
// MODE 1: 4 waves (2x2), 128x64 tile, 16KB LDS; fp32 out + bias.
// 1-D grid, XCD swizzle: mb=(bid&7)*8+((bid>>3)&7), nb=bid>>6.
template<int MODE>
__global__ __launch_bounds__(MODE == 0 ? 512 : 256, 4)
void gemm_frag(const unsigned short* __restrict__ Af,
               const unsigned short* __restrict__ Bf,
               const float* __restrict__ bias,
               float* __restrict__ outF,
               unsigned short* __restrict__ outQ,
               unsigned short* __restrict__ outK,
               unsigned short* __restrict__ outV)
{
    constexpr int NW     = (MODE == 0) ? 8 : 4;     // waves per block
    constexpr int NSUB_N = (MODE == 0) ? 8 : 4;     // B subtiles per block
    constexpr int ACH    = 8;                       // A hi 1KB-chunks per kt
    constexpr int NCH    = ACH + 2 * NSUB_N;        // chunks per kt (24 / 16)
    __shared__ unsigned short Asm[ACH * 512];
    __shared__ unsigned short Bsm[NSUB_N * 1024];
    const int t = threadIdx.x, lane = t & 63, wid = t >> 6;
    const int wr = (MODE == 0) ? (wid >> 2) : (wid >> 1);
    const int wc = (MODE == 0) ? (wid & 3)  : (wid & 1);
    const int bid = blockIdx.x;
    const int mb = (bid & 7) * 8 + ((bid >> 3) & 7);
    const int nb = bid >> 6;

    f32x4 acc[4][2] = {};

    for (int kt = 0; kt < KT_D; ++kt) {
        __syncthreads();                       // prior LDS reads done
        // stage NCH 1KB chunks, NCH/NW per wave
        #pragma unroll
        for (int i = 0; i < NCH/NW; ++i) {
            const int c = wid * (NCH/NW) + i;
            if (c < ACH) {                     // A hi-only subtile c
                const unsigned short* g =
                    Af + ((size_t)(mb*8 + c)*KT_D + kt)*512 + lane*8;
                gload16(g, (const char*)Asm + (size_t)c*1024);
            } else {                           // B subtile j>>1, plane j&1
                const int j = c - ACH;
                const unsigned short* g =
                    Bf + ((size_t)(nb*NSUB_N + (j >> 1))*KT_D + kt)*1024 + (j & 1)*512 + lane*8;
                gload16(g, (const char*)Bsm + (size_t)j*1024);
            }
        }
        __syncthreads();                       // staging complete (vmcnt drained)

        bf16x8 bh[2], bl[2];
        #pragma unroll
        for (int n = 0; n < 2; ++n) {
            bh[n] = *(const bf16x8*)(Bsm + (wc*2 + n)*1024 + lane*8);
            bl[n] = *(const bf16x8*)(Bsm + (wc*2 + n)*1024 + 512 + lane*8);
        }
        bf16x8 ah[4];
        #pragma unroll
        for (int m = 0; m < 4; ++m)
            ah[m] = *(const bf16x8*)(Asm + (wr*4 + m)*512 + lane*8);
        #pragma unroll
        for (int m = 0; m < 4; ++m)
            #pragma unroll
            for (int n = 0; n < 2; ++n) {
                acc[m][n] = MFMA16(ah[m], bh[n], acc[m][n]);
                acc[m][n] = MFMA16(ah[m], bl[n], acc[m][n]);
            }
    }

    const int rowW = mb*128 + wr*64;
    const int colW = nb*(NSUB_N*16) + wc*32;
    if (MODE == 1) {
        #pragma unroll
        for (int m = 0; m < 4; ++m)
            #pragma unroll
            for (int n = 0; n < 2; ++n) {
                const int col = colW + n*16 + (lane & 15);
                const float bv = bias[col];
                #pragma unroll
                for (int r = 0; r < 4; ++r) {
                    const int row = rowW + m*16 + (lane >> 4)*4 + r;
                    outF[(size_t)row * D_MODEL + col] = acc[m][n][r] + bv;
                }
            }
    } else {
        // wave-uniform (which, head): colW..colW+31 stays inside one head (64-wide)
        const int which = colW / D_MODEL;
        const int h     = (colW % D_MODEL) >> 6;
        #pragma unroll
        for (int m = 0; m < 4; ++m)
            #pragma unroll
            for (int n = 0; n < 2; ++n) {
                const int col = colW + n*16 + (lane & 15);
                const int d = col & 63;
                const float bv = bias[col];
                #pragma unroll
                for (int r = 0; r < 4; ++r) {
                    const int row = rowW + m*16 + (lane >> 4)*4 + r;
                    const int b = row >> 10, sq = row & 1023;
                    float val = acc[m][n][r] + bv;
                    if (which == 0) {                    // Q: full hi+lo, pre-scaled
                        val *= QSCALE;
                        const int sub = (sq >> 4)*2 + (d >> 5);
                        const int lp  = (sq & 15) + (((d & 31) >> 3) << 4);
                        unsigned short hi, lo; split2(val, hi, lo);
                        unsigned short* p = outQ + (size_t)(b*NHEADS + h)*131072
                                          + (size_t)sub*1024 + lp*8 + (d & 7);
                        p[0]   = hi;
                        p[512] = lo;
                    } else if (which == 1) {             // K: hi only
                        const int sub = (sq >> 4)*2 + (d >> 5);
                        const int lp  = (sq & 15) + (((d & 31) >> 3) << 4);
                        outK[(size_t)(b*NHEADS + h)*65536
                             + (size_t)sub*512 + lp*8 + (d & 7)] = f2bf(val);
                    } else {                             // V: hi only (B-frag)
                        const int sub = (d >> 4)*32 + (sq >> 5);
                        const int lp  = (d & 15) + (((sq & 31) >> 3) << 4);
                        outV[(size_t)(b*NHEADS + h)*65536
                             + (size_t)sub*512 + lp*8 + (sq & 7)] = f2bf(val);
                    }
                }
            }
    }
}

// ---- flash attention: 8 waves x 16 q-rows (1 m-subtile/wave), KV tiles of 64 -
// dbuf staging; K,V hi-only; QK split-2; PV hi-only; MFMA-ones rowsum;
// defer-max THR=8; exp2 domain. 24 waves/CU. Epilogue: hi-only Cf fragments.
__global__ __launch_bounds__(512, 6)
void attn_frag(const unsigned short* __restrict__ Qf,
               const unsigned short* __restrict__ Kf,
               const unsigned short* __restrict__ Vf,
               unsigned short* __restrict__ Cf)
{
    __shared__ unsigned short Ksm[2][8 * 512];   // dbuf: 4 jn x 2 kt hi subtiles
    __shared__ unsigned short Vsm[2][8 * 512];   // dbuf: 4 dt x 2 kt2 hi subtiles
    __shared__ unsigned short Psm[8 * 1024];     // per-wave P: 2 subtiles x 512 bf16

    const int t = threadIdx.x, lane = t & 63, wid = t >> 6;   // wid 0..7
    // XCD swizzle: all 8 q-blocks of one (b,h) land on the same XCD
    const int bid = blockIdx.x;
    const int qb  = (bid >> 3) & 7;
    const int bh  = (bid & 7) * 12 + (bid >> 6);
    const int mt0 = qb*8 + wid;                // wave's q-subtile (of 64)
    const size_t qBase = (size_t)bh * 131072;
    const size_t kBase = (size_t)bh * 65536;

    const int slot  = lane & 7;
    const int colg  = (lane & 15) >> 3;        // 0/1
    const int qrow0 = (lane >> 4) * 4;         // 0,4,8,12

    // stage K/V hi subtiles of kv-tile jt into buffer b (2 chunks per wave)
    auto stage = [&](int b, int jt) {
        #pragma unroll
        for (int i = 0; i < 2; ++i) {
            const int ch = wid*2 + i;
            if (ch < 8) {
                const unsigned short* gk = Kf + kBase + (size_t)(jt*8 + ch)*512;
                gload16(gk + lane*8, (const char*)&Ksm[b][0] + (size_t)ch*1024);
            } else {
                const int cv = ch - 8;                 // dt = cv>>1, kt2 = cv&1
                const unsigned short* gv = Vf + kBase
                    + (size_t)((cv >> 1)*32 + jt*2 + (cv & 1))*512;
                gload16(gv + lane*8, (const char*)&Vsm[b][0] + (size_t)cv*1024);
            }
        }
    };

    stage(0, 0);                               // prologue: tile 0 into buf 0

    // Q fragments in registers (already scaled by QSCALE); overlap prologue.
    bf16x8 qh[2], ql[2];
    #pragma unroll
    for (int kt = 0; kt < 2; ++kt) {
        const unsigned short* p = Qf + qBase + ((size_t)mt0*2 + kt)*1024 + lane*8;
        qh[kt] = *(const bf16x8*)(p);
        ql[kt] = *(const bf16x8*)(p + 512);
    }

    // ones B-frag for the MFMA rowsum
    bf16x8 ones;
    #pragma unroll
    for (int i = 0; i < 8; ++i) ones[i] = (short)0x3F80;

    f32x4 out[4] = {};
    f32x4 lacc = {};
    float m_run[4];
    #pragma unroll
    for (int r = 0; r < 4; ++r) m_run[r] = -INFINITY;

    unsigned short* Pw = Psm + wid * 1024;

    __syncthreads();                           // prologue stage complete

    for (int jt = 0; jt < 16; ++jt) {
        const int cur = jt & 1;
        if (jt + 1 < 16) stage(cur ^ 1, jt + 1);   // prefetch next tile (hidden)

        // S = Q K^T, split-2 (K hi only)
        f32x4 s[4] = {};
        #pragma unroll
        for (int jn = 0; jn < 4; ++jn)
            #pragma unroll
            for (int kt = 0; kt < 2; ++kt) {
                const bf16x8 kh = *(const bf16x8*)(&Ksm[cur][0] + (jn*2 + kt)*512 + lane*8);
                s[jn] = MFMA16(qh[kt], kh, s[jn]);
                s[jn] = MFMA16(ql[kt], kh, s[jn]);
            }

        // defer-max: in-lane partial max -> wave-uniform skip predicate
        float mx[4];
        int ok = 1;
        #pragma unroll
        for (int r = 0; r < 4; ++r) {
            const float v = fmaxf(fmaxf(s[0][r], s[1][r]), fmaxf(s[2][r], s[3][r]));
            mx[r] = v;
            ok &= (v <= m_run[r] + 8.0f);
        }
        if (!__all(ok)) {
            float alf[4];
            #pragma unroll
            for (int r = 0; r < 4; ++r) {
                float v = mx[r];
                #pragma unroll
                for (int msk = 1; msk < 16; msk <<= 1)
                    v = fmaxf(v, __shfl_xor(v, msk));
                const float mn = fmaxf(m_run[r], v);
                alf[r] = exp2_fast(m_run[r] - mn);
                m_run[r] = mn;
            }
            #pragma unroll
            for (int dt = 0; dt < 4; ++dt)
                #pragma unroll
                for (int r = 0; r < 4; ++r)
                    out[dt][r] *= alf[r];
            #pragma unroll
            for (int r = 0; r < 4; ++r)
                lacc[r] *= alf[r];
        }

        // P = exp2(s - m) -> bf16-hi into swizzled A-frag LDS (wave-local)
        #pragma unroll
        for (int r = 0; r < 4; ++r) {
            const float mb_ = m_run[r];
            const int tl   = qrow0 + r + (colg << 4);
            const int idxb = ((tl << 3) | slot) ^ (tl & 0x18);
            #pragma unroll
            for (int jn = 0; jn < 4; ++jn)
                Pw[(jn >> 1)*512 + idxb + ((jn & 1) << 8)]
                    = f2bf(exp2_fast(s[jn][r] - mb_));
        }

        // PV + MFMA rowsum: read P back as bf16x8 A-frags (wave-local)
        const int rdswz = (lane*8) ^ (lane & 0x18);
        #pragma unroll
        for (int kt2 = 0; kt2 < 2; ++kt2) {
            const bf16x8 pa = *(const bf16x8*)(Pw + kt2*512 + rdswz);
            #pragma unroll
            for (int dt = 0; dt < 4; ++dt) {
                const bf16x8 vh = *(const bf16x8*)(&Vsm[cur][0] + (dt*2 + kt2)*512 + lane*8);
                out[dt] = MFMA16(pa, vh, out[dt]);
            }
            lacc = MFMA16(pa, ones, lacc);
        }

        __syncthreads();   // next tile staged by ALL waves; this tile's reads done
    }

    // epilogue: ctx / l -> proj-GEMM A-fragments, HI-ONLY
    const int b = bh / NHEADS, h = bh % NHEADS;
    #pragma unroll
    for (int r = 0; r < 4; ++r) {
        const float inv = 1.0f / lacc[r];
        const int sq = mt0*16 + qrow0 + r;
        const int mrow = b*SEQ + sq;
        #pragma unroll
        for (int dt = 0; dt < 4; ++dt) {
            const int c = h*64 + dt*16 + (lane & 15);
            const float val = out[dt][r] * inv;
            Cf[((size_t)(mrow >> 4)*KT_D + (c >> 5))*512
               + ((mrow & 15) + (((c & 31) >> 3) << 4))*8 + (c & 7)] = f2bf(val);
        }
    }
}

// ---------------------------------------------------------------------------
extern "C" void kernel_launch(void* const* d_in, const int* in_sizes, int n_in,
                              void* d_out, int out_size, void* d_ws, size_t ws_size,
                              hipStream_t stream)
{
    const float* x      = (const float*)d_in[0];
    const float* w_qkv  = (const float*)d_in[1];
    const float* b_qkv  = (const float*)d_in[2];
    const float* w_proj = (const float*)d_in[3];
    const float* b_proj = (const float*)d_in[4];
    float* out = (float*)d_out;

    unsigned short* ws = (unsigned short*)d_ws;
    unsigned short* Xf = ws;                    // 12288 sub * 512    =  6,291,456
    unsigned short* Wq = Xf + 6291456;          // 3456 sub * 1024    =  3,538,944
    unsigned short* Wp = Wq + 3538944;          // 1152 sub * 1024    =  1,179,648
    unsigned short* Qf = Wp + 1179648;          // 96 * 131072        = 12,582,912
    unsigned short* Kf = Qf + 12582912;         // 96 * 65536         =  6,291,456
    unsigned short* Vf = Kf + 6291456;          // 96 * 65536         =  6,291,456
    unsigned short* Cf = Vf + 6291456;          // 12288 sub * 512    =  6,291,456
    // total ~43.4M ushorts = ~83 MB of d_ws

    convert_a<<<dim3(3072), 256, 0, stream>>>(x, Xf, 786432);
    convert_b<<<dim3(864),  256, 0, stream>>>(w_qkv, Wq, QKV_COLS, 221184);
    convert_b<<<dim3(288),  256, 0, stream>>>(w_proj, Wp, D_MODEL, 73728);

    // gemm0: 128x128 tiles -> grid 64 x 18 = 1152 (mb-swizzled, nb = bid>>6)
    gemm_frag<0><<<dim3(1152), 512, 0, stream>>>(Xf, Wq, b_qkv, nullptr, Qf, Kf, Vf);
    attn_frag<<<dim3(768), 512, 0, stream>>>(Qf, Kf, Vf, Cf);
    // gemm1: 128x64 tiles -> grid 64 x 12 = 768
    gemm_frag<1><<<dim3(768), 256, 0, stream>>>(Cf, Wp, b_proj, out,
                                                nullptr, nullptr, nullptr);
}